// Round 1
// baseline (617.217 us; speedup 1.0000x reference)
//
#include <hip/hip_runtime.h>
#include <stdint.h>

// ---------------------------------------------------------------------------
// WindowedSelfAttentionLayer: B=2 S=2048 D=1024 H=16 DH=64 HID=4096 WIN=256
// All GEMMs: bf16 MFMA 16x16x32, 128x128 tile, BK=64, 4 waves (m97 structure).
// ---------------------------------------------------------------------------

typedef __bf16 bf16;
typedef bf16  bf16x8 __attribute__((ext_vector_type(8)));
typedef bf16  bf16x4v __attribute__((ext_vector_type(4)));
typedef bf16  bf16x2v __attribute__((ext_vector_type(2)));
typedef float f32x4  __attribute__((ext_vector_type(4)));

#define S_LEN 2048
#define NQKV  3072

// global -> LDS direct copy, 16B per lane. LDS dest must be wave-uniform base;
// data lands at base + lane*16.
#define GLDS16(gp, lp)                                                          \
  __builtin_amdgcn_global_load_lds(                                            \
      (__attribute__((address_space(1))) void*)(gp),                            \
      (__attribute__((address_space(3))) void*)(lp), 16, 0, 0)

// ---------------------------------------------------------------------------
// LayerNorm (fp32 in) -> bf16 out.  One block (256 thr) per 1024-dim row.
// ---------------------------------------------------------------------------
__global__ __launch_bounds__(256) void ln_bf16(const float* __restrict__ x,
                                               const float* __restrict__ w,
                                               const float* __restrict__ bb,
                                               bf16* __restrict__ out) {
  const int row = blockIdx.x, tid = threadIdx.x;
  const int wid = tid >> 6, lane = tid & 63;
  const float4 v = ((const float4*)(x + (size_t)row * 1024))[tid];
  float s = v.x + v.y + v.z + v.w;
  float q = v.x * v.x + v.y * v.y + v.z * v.z + v.w * v.w;
#pragma unroll
  for (int off = 32; off > 0; off >>= 1) {
    s += __shfl_xor(s, off);
    q += __shfl_xor(q, off);
  }
  __shared__ float rs_[4], rq_[4];
  if (lane == 0) { rs_[wid] = s; rq_[wid] = q; }
  __syncthreads();
  s = rs_[0] + rs_[1] + rs_[2] + rs_[3];
  q = rq_[0] + rq_[1] + rq_[2] + rq_[3];
  const float mean = s * (1.f / 1024.f);
  const float var  = q * (1.f / 1024.f) - mean * mean;
  const float rstd = rsqrtf(var + 1e-5f);
  const float4 wv = ((const float4*)w)[tid];
  const float4 bv = ((const float4*)bb)[tid];
  bf16x4v o;
  o[0] = (bf16)((v.x - mean) * rstd * wv.x + bv.x);
  o[1] = (bf16)((v.y - mean) * rstd * wv.y + bv.y);
  o[2] = (bf16)((v.z - mean) * rstd * wv.z + bv.z);
  o[3] = (bf16)((v.w - mean) * rstd * wv.w + bv.w);
  ((bf16x4v*)(out + (size_t)row * 1024))[tid] = o;
}

// ---------------------------------------------------------------------------
// Transpose + cast: in fp32 [R][C] -> out bf16 [C][R].  R,C multiples of 32.
// ---------------------------------------------------------------------------
__global__ __launch_bounds__(256) void tr_cast(const float* __restrict__ in,
                                               bf16* __restrict__ out, int R, int C) {
  __shared__ float t[32][33];
  const int tx = threadIdx.x, ty = threadIdx.y;
  const int r0 = blockIdx.y * 32, c0 = blockIdx.x * 32;
#pragma unroll
  for (int i = 0; i < 4; ++i)
    t[ty + 8 * i][tx] = in[(size_t)(r0 + ty + 8 * i) * C + c0 + tx];
  __syncthreads();
#pragma unroll
  for (int i = 0; i < 4; ++i)
    out[(size_t)(c0 + ty + 8 * i) * R + r0 + tx] = (bf16)t[tx][ty + 8 * i];
}

__global__ void concat3(const float* __restrict__ a, const float* __restrict__ b,
                        const float* __restrict__ c, float* __restrict__ o) {
  int i = blockIdx.x * 256 + threadIdx.x;
  if (i < 1024) o[i] = a[i];
  else if (i < 2048) o[i] = b[i - 1024];
  else if (i < 3072) o[i] = c[i - 2048];
}

// ---------------------------------------------------------------------------
// GEMM: C[M][N] = A[M][K](bf16) * BT[N][K](bf16)^T + bias (+epilogue)
// EPI 0: bf16 out.  EPI 1: fp32 out with fp32 residual add.
// EPI 2: silu(g)*u fused -> bf16 out  (acc is the u-path, gbuf holds g).
// 128x128 tile, BK=64, 256 threads = 4 waves (2x2 of 64x64 each).
// ---------------------------------------------------------------------------
template <int EPI>
__global__ __launch_bounds__(256) void gemm_bf16t(
    const bf16* __restrict__ A, const bf16* __restrict__ BT,
    const float* __restrict__ bias, const float* __restrict__ res,
    const bf16* __restrict__ gbuf, void* __restrict__ Cout,
    int M, int N, int K) {
  __shared__ bf16 sA[128 * 64];
  __shared__ bf16 sB[128 * 64];
  const int tid = threadIdx.x;
  const int wid = tid >> 6, lane = tid & 63;
  const int m0 = blockIdx.y * 128, n0 = blockIdx.x * 128;
  const int wm = (wid >> 1) * 64, wn = (wid & 1) * 64;
  const int lrow = lane >> 3, lseg = (lane & 7) * 8;
  const int fr = lane & 15, fq = lane >> 4;

  f32x4 acc[4][4];
#pragma unroll
  for (int i = 0; i < 4; ++i)
#pragma unroll
    for (int j = 0; j < 4; ++j) acc[i][j] = f32x4{0.f, 0.f, 0.f, 0.f};

  for (int k0 = 0; k0 < K; k0 += 64) {
#pragma unroll
    for (int it = 0; it < 4; ++it) {
      const int c = wid * 4 + it;         // 16 chunks of 1KB each per tile
      const int row = c * 8 + lrow;
      GLDS16(A  + (size_t)(m0 + row) * K + k0 + lseg, sA + c * 512);
      GLDS16(BT + (size_t)(n0 + row) * K + k0 + lseg, sB + c * 512);
    }
    __syncthreads();
#pragma unroll
    for (int kk = 0; kk < 64; kk += 32) {
      bf16x8 af[4], bfv[4];
#pragma unroll
      for (int i = 0; i < 4; ++i)
        af[i] = *(const bf16x8*)(sA + (wm + i * 16 + fr) * 64 + kk + 8 * fq);
#pragma unroll
      for (int j = 0; j < 4; ++j)
        bfv[j] = *(const bf16x8*)(sB + (wn + j * 16 + fr) * 64 + kk + 8 * fq);
#pragma unroll
      for (int i = 0; i < 4; ++i)
#pragma unroll
        for (int j = 0; j < 4; ++j)
          acc[i][j] = __builtin_amdgcn_mfma_f32_16x16x32_bf16(af[i], bfv[j],
                                                              acc[i][j], 0, 0, 0);
    }
    __syncthreads();
  }

#pragma unroll
  for (int i = 0; i < 4; ++i) {
    const int grow = m0 + wm + i * 16 + fq * 4;
#pragma unroll
    for (int j = 0; j < 4; ++j) {
      const int gcol = n0 + wn + j * 16 + fr;
      const float bc = bias[gcol];
#pragma unroll
      for (int r = 0; r < 4; ++r) {
        const size_t idx = (size_t)(grow + r) * N + gcol;
        const float v = acc[i][j][r] + bc;
        if constexpr (EPI == 0) {
          ((bf16*)Cout)[idx] = (bf16)v;
        } else if constexpr (EPI == 1) {
          ((float*)Cout)[idx] = v + res[idx];
        } else {
          const float gg = (float)gbuf[idx];
          ((bf16*)Cout)[idx] = (bf16)(v * gg / (1.f + __expf(-gg)));
        }
      }
    }
  }
}

// ---------------------------------------------------------------------------
// Windowed attention.  qkv bf16 [B*S][3072] (q|k|v each [h*64+dh]).
// One block per (b*H+h, 64-query tile).  4 waves x 16 queries.
// Keys staged: 320 rows = [qs0-128, qs0+191], clamped addresses (masked later).
// ---------------------------------------------------------------------------
__global__ __launch_bounds__(256) void attn_win(const bf16* __restrict__ qkv,
                                                bf16* __restrict__ ctx) {
  __shared__ bf16 sK[320 * 64];
  __shared__ bf16 sV[320 * 64];
  __shared__ bf16 sQ[64 * 64];
  __shared__ float sP[4][320];
  const int bh = blockIdx.x;
  const int b = bh >> 4, h = bh & 15;
  const int qs0 = blockIdx.y * 64;
  const int t0 = qs0 - 128;
  const int tid = threadIdx.x, wid = tid >> 6, lane = tid & 63;
  const size_t bbase = (size_t)b * S_LEN;

  // stage K,V (40 chunks each) and Q (8 chunks), 8 rows of 128B per chunk
#pragma unroll
  for (int it = 0; it < 10; ++it) {
    const int c = wid * 10 + it;
    const int rr = c * 8 + (lane >> 3);
    int t = t0 + rr;
    t = t < 0 ? 0 : (t > S_LEN - 1 ? S_LEN - 1 : t);  // clamp: finite garbage, masked
    const bf16* gp = qkv + (bbase + t) * NQKV + 1024 + h * 64 + (lane & 7) * 8;
    GLDS16(gp, sK + c * 512);
    GLDS16(gp + 1024, sV + c * 512);
  }
#pragma unroll
  for (int it = 0; it < 2; ++it) {
    const int c = wid * 2 + it;
    const int rr = c * 8 + (lane >> 3);
    const bf16* gp = qkv + (bbase + qs0 + rr) * NQKV + h * 64 + (lane & 7) * 8;
    GLDS16(gp, sQ + c * 512);
  }
  __syncthreads();

  const int dw = lane & 31, half = lane >> 5;
  for (int qi = 0; qi < 16; ++qi) {
    const int m = wid * 16 + qi;          // query row within 64-tile
    // ---- scores: 5 keys per lane, packed bf16-pair dot, conflict-free ----
    const uint32_t* qrow = (const uint32_t*)(sQ + m * 64);
    float sc[5] = {0.f, 0.f, 0.f, 0.f, 0.f};
#pragma unroll 4
    for (int dp = 0; dp < 32; ++dp) {
      const int di = (dp + lane) & 31;
      const uint32_t qu = qrow[di];
      const float q0 = __uint_as_float(qu << 16);
      const float q1 = __uint_as_float(qu & 0xffff0000u);
#pragma unroll
      for (int j = 0; j < 5; ++j) {
        const uint32_t ku = ((const uint32_t*)(sK + (lane + 64 * j) * 64))[di];
        sc[j] += q0 * __uint_as_float(ku << 16) + q1 * __uint_as_float(ku & 0xffff0000u);
      }
    }
    // ---- mask + softmax (wave-wide butterflies) ----
    float mx = -1e30f, scv[5];
#pragma unroll
    for (int j = 0; j < 5; ++j) {
      const int tr = lane + 64 * j;
      const int t = t0 + tr;
      const bool ok = (tr >= m) && (tr <= m + 256) && (t >= 0) && (t < S_LEN);
      scv[j] = ok ? sc[j] * 0.125f : -1e30f;
      mx = fmaxf(mx, scv[j]);
    }
#pragma unroll
    for (int off = 32; off > 0; off >>= 1) mx = fmaxf(mx, __shfl_xor(mx, off));
    float sum = 0.f, p[5];
#pragma unroll
    for (int j = 0; j < 5; ++j) { p[j] = __expf(scv[j] - mx); sum += p[j]; }
#pragma unroll
    for (int off = 32; off > 0; off >>= 1) sum += __shfl_xor(sum, off);
    const float inv = 1.f / sum;
#pragma unroll
    for (int j = 0; j < 5; ++j) sP[wid][lane + 64 * j] = p[j] * inv;
    __syncthreads();
    // ---- PV: lane owns dword dw (dims 2dw,2dw+1); halves split the 257 keys ----
    float c0 = 0.f, c1 = 0.f;
    const int base = m + half * 128;
    for (int tt = 0; tt <= 128; ++tt) {
      const int tr = base + tt;
      float pp = sP[wid][tr];
      if (half == 0 && tt == 128) pp = 0.f;  // avoid double-count of tr=m+128
      const uint32_t vv = ((const uint32_t*)(sV + tr * 64))[dw];
      c0 += pp * __uint_as_float(vv << 16);
      c1 += pp * __uint_as_float(vv & 0xffff0000u);
    }
    c0 += __shfl_xor(c0, 32);
    c1 += __shfl_xor(c1, 32);
    if (lane < 32) {
      bf16x2v o;
      o[0] = (bf16)c0;
      o[1] = (bf16)c1;
      *(bf16x2v*)(ctx + (bbase + qs0 + m) * 1024 + h * 64 + 2 * dw) = o;
    }
  }
}

// ---------------------------------------------------------------------------
extern "C" void kernel_launch(void* const* d_in, const int* in_sizes, int n_in,
                              void* d_out, int out_size, void* d_ws, size_t ws_size,
                              hipStream_t stream) {
  const float* x    = (const float*)d_in[0];
  const float* ln1w = (const float*)d_in[2];
  const float* ln1b = (const float*)d_in[3];
  const float* Wq   = (const float*)d_in[4];
  const float* bq   = (const float*)d_in[5];
  const float* Wk   = (const float*)d_in[6];
  const float* bk   = (const float*)d_in[7];
  const float* Wv   = (const float*)d_in[8];
  const float* bv   = (const float*)d_in[9];
  const float* Wo   = (const float*)d_in[10];
  const float* bo   = (const float*)d_in[11];
  const float* ln2w = (const float*)d_in[12];
  const float* ln2b = (const float*)d_in[13];
  const float* Wg   = (const float*)d_in[14];
  const float* bg   = (const float*)d_in[15];
  const float* Wu   = (const float*)d_in[16];
  const float* bu   = (const float*)d_in[17];
  const float* Wd   = (const float*)d_in[18];
  const float* bd   = (const float*)d_in[19];

  char* ws = (char*)d_ws;
  size_t off = 0;
  auto take = [&](size_t bytes) {
    char* p = ws + off;
    off += (bytes + 255) & ~(size_t)255;
    return p;
  };
  bf16*  wqkvT = (bf16*)take((size_t)3072 * 1024 * 2);
  bf16*  woT   = (bf16*)take((size_t)1024 * 1024 * 2);
  bf16*  wgT   = (bf16*)take((size_t)4096 * 1024 * 2);
  bf16*  wuT   = (bf16*)take((size_t)4096 * 1024 * 2);
  bf16*  wdT   = (bf16*)take((size_t)1024 * 4096 * 2);
  float* bqkv  = (float*)take((size_t)3072 * 4);
  bf16*  h     = (bf16*)take((size_t)4096 * 1024 * 2);
  bf16*  qkv   = (bf16*)take((size_t)4096 * 3072 * 2);
  bf16*  ctx   = (bf16*)take((size_t)4096 * 1024 * 2);
  float* x1    = (float*)take((size_t)4096 * 1024 * 4);
  bf16*  h2    = (bf16*)take((size_t)4096 * 1024 * 2);
  bf16*  g     = (bf16*)take((size_t)4096 * 4096 * 2);
  bf16*  gated = (bf16*)take((size_t)4096 * 4096 * 2);
  (void)ws_size; (void)in_sizes; (void)n_in; (void)out_size;

  const dim3 tb(32, 8);
  // weight prep: W[K][N] fp32 -> WT[N][K] bf16
  tr_cast<<<dim3(32, 32), tb, 0, stream>>>(Wq, wqkvT, 1024, 1024);
  tr_cast<<<dim3(32, 32), tb, 0, stream>>>(Wk, wqkvT + (size_t)1024 * 1024, 1024, 1024);
  tr_cast<<<dim3(32, 32), tb, 0, stream>>>(Wv, wqkvT + (size_t)2048 * 1024, 1024, 1024);
  tr_cast<<<dim3(32, 32), tb, 0, stream>>>(Wo, woT, 1024, 1024);
  tr_cast<<<dim3(128, 32), tb, 0, stream>>>(Wg, wgT, 1024, 4096);
  tr_cast<<<dim3(128, 32), tb, 0, stream>>>(Wu, wuT, 1024, 4096);
  tr_cast<<<dim3(32, 128), tb, 0, stream>>>(Wd, wdT, 4096, 1024);
  concat3<<<12, 256, 0, stream>>>(bq, bk, bv, bqkv);

  // LN1 -> h
  ln_bf16<<<4096, 256, 0, stream>>>(x, ln1w, ln1b, h);
  // QKV: [4096,3072] = h @ Wqkv + b  -> bf16
  gemm_bf16t<0><<<dim3(24, 32), 256, 0, stream>>>(h, wqkvT, bqkv, nullptr, nullptr,
                                                  qkv, 4096, 3072, 1024);
  // windowed attention -> ctx bf16
  attn_win<<<dim3(32, 32), 256, 0, stream>>>(qkv, ctx);
  // x1 = x + ctx @ Wo + bo
  gemm_bf16t<1><<<dim3(8, 32), 256, 0, stream>>>(ctx, woT, bo, x, nullptr,
                                                 x1, 4096, 1024, 1024);
  // LN2 -> h2
  ln_bf16<<<4096, 256, 0, stream>>>(x1, ln2w, ln2b, h2);
  // g = h2 @ Wg + bg (bf16)
  gemm_bf16t<0><<<dim3(32, 32), 256, 0, stream>>>(h2, wgT, bg, nullptr, nullptr,
                                                  g, 4096, 4096, 1024);
  // gated = silu(g) * (h2 @ Wu + bu)  (bf16)
  gemm_bf16t<2><<<dim3(32, 32), 256, 0, stream>>>(h2, wuT, bu, nullptr, g,
                                                  gated, 4096, 4096, 1024);
  // out = x1 + gated @ Wd + bd  (fp32)
  gemm_bf16t<1><<<dim3(8, 32), 256, 0, stream>>>(gated, wdT, bd, x1, nullptr,
                                                 d_out, 4096, 1024, 4096);
}

// Round 2
// 347.862 us; speedup vs baseline: 1.7743x; 1.7743x over previous
//
#include <hip/hip_runtime.h>
#include <stdint.h>

// ---------------------------------------------------------------------------
// WindowedSelfAttentionLayer: B=2 S=2048 D=1024 H=16 DH=64 HID=4096 WIN=256
// GEMMs: bf16 MFMA 16x16x32, 128x128 tile, BK=64, 4 waves (m97 structure).
// Attention: MFMA flash-style per (b,h,64-query tile), V^T produced by the
// QKV GEMM epilogue.
// ---------------------------------------------------------------------------

typedef __bf16 bf16;
typedef bf16  bf16x8 __attribute__((ext_vector_type(8)));
typedef bf16  bf16x4v __attribute__((ext_vector_type(4)));
typedef float f32x4  __attribute__((ext_vector_type(4)));

#define S_LEN 2048
#define NQKV  3072

// global -> LDS direct copy, 16B per lane (wave-uniform LDS base).
#define GLDS16(gp, lp)                                                          \
  __builtin_amdgcn_global_load_lds(                                            \
      (__attribute__((address_space(1))) void*)(gp),                            \
      (__attribute__((address_space(3))) void*)(lp), 16, 0, 0)

// ---------------------------------------------------------------------------
// LayerNorm (fp32 in) -> bf16 out.  One block (256 thr) per 1024-dim row.
// ---------------------------------------------------------------------------
__global__ __launch_bounds__(256) void ln_bf16(const float* __restrict__ x,
                                               const float* __restrict__ w,
                                               const float* __restrict__ bb,
                                               bf16* __restrict__ out) {
  const int row = blockIdx.x, tid = threadIdx.x;
  const int wid = tid >> 6, lane = tid & 63;
  const float4 v = ((const float4*)(x + (size_t)row * 1024))[tid];
  float s = v.x + v.y + v.z + v.w;
  float q = v.x * v.x + v.y * v.y + v.z * v.z + v.w * v.w;
#pragma unroll
  for (int off = 32; off > 0; off >>= 1) {
    s += __shfl_xor(s, off);
    q += __shfl_xor(q, off);
  }
  __shared__ float rs_[4], rq_[4];
  if (lane == 0) { rs_[wid] = s; rq_[wid] = q; }
  __syncthreads();
  s = rs_[0] + rs_[1] + rs_[2] + rs_[3];
  q = rq_[0] + rq_[1] + rq_[2] + rq_[3];
  const float mean = s * (1.f / 1024.f);
  const float var  = q * (1.f / 1024.f) - mean * mean;
  const float rstd = rsqrtf(var + 1e-5f);
  const float4 wv = ((const float4*)w)[tid];
  const float4 bv = ((const float4*)bb)[tid];
  bf16x4v o;
  o[0] = (bf16)((v.x - mean) * rstd * wv.x + bv.x);
  o[1] = (bf16)((v.y - mean) * rstd * wv.y + bv.y);
  o[2] = (bf16)((v.z - mean) * rstd * wv.z + bv.z);
  o[3] = (bf16)((v.w - mean) * rstd * wv.w + bv.w);
  ((bf16x4v*)(out + (size_t)row * 1024))[tid] = o;
}

// ---------------------------------------------------------------------------
// Transpose + cast: in fp32 [R][C] -> out bf16 [C][R].
// ---------------------------------------------------------------------------
__global__ __launch_bounds__(256) void tr_cast(const float* __restrict__ in,
                                               bf16* __restrict__ out, int R, int C) {
  __shared__ float t[32][33];
  const int tx = threadIdx.x, ty = threadIdx.y;
  const int r0 = blockIdx.y * 32, c0 = blockIdx.x * 32;
#pragma unroll
  for (int i = 0; i < 4; ++i)
    t[ty + 8 * i][tx] = in[(size_t)(r0 + ty + 8 * i) * C + c0 + tx];
  __syncthreads();
#pragma unroll
  for (int i = 0; i < 4; ++i)
    out[(size_t)(c0 + ty + 8 * i) * R + r0 + tx] = (bf16)t[tx][ty + 8 * i];
}

__global__ void concat3(const float* __restrict__ a, const float* __restrict__ b,
                        const float* __restrict__ c, float* __restrict__ o) {
  int i = blockIdx.x * 256 + threadIdx.x;
  if (i < 1024) o[i] = a[i];
  else if (i < 2048) o[i] = b[i - 1024];
  else if (i < 3072) o[i] = c[i - 2048];
}

// ---------------------------------------------------------------------------
// GEMM: C[M][N] = A[M][K](bf16) * BT[N][K](bf16)^T + bias (+epilogue)
// EPI 0: bf16 out.  EPI 1: fp32 out + fp32 residual.
// EPI 2: silu(g)*u fused -> bf16 (acc = u-path, gbuf = g).
// EPI 3: QKV — cols <2048 (Q|K) -> bf16 Cout; cols >=2048 (V) -> transposed
//        vout[b*1024 + (col-2048)][t] as packed bf16x4 (4 rows = 4 consec t).
// ---------------------------------------------------------------------------
template <int EPI>
__global__ __launch_bounds__(256) void gemm_bf16t(
    const bf16* __restrict__ A, const bf16* __restrict__ BT,
    const float* __restrict__ bias, const float* __restrict__ res,
    const bf16* __restrict__ gbuf, bf16* __restrict__ vout,
    void* __restrict__ Cout, int M, int N, int K) {
  __shared__ bf16 sA[128 * 64];
  __shared__ bf16 sB[128 * 64];
  const int tid = threadIdx.x;
  const int wid = tid >> 6, lane = tid & 63;
  const int m0 = blockIdx.y * 128, n0 = blockIdx.x * 128;
  const int wm = (wid >> 1) * 64, wn = (wid & 1) * 64;
  const int lrow = lane >> 3, lseg = (lane & 7) * 8;
  const int fr = lane & 15, fq = lane >> 4;

  f32x4 acc[4][4];
#pragma unroll
  for (int i = 0; i < 4; ++i)
#pragma unroll
    for (int j = 0; j < 4; ++j) acc[i][j] = f32x4{0.f, 0.f, 0.f, 0.f};

  for (int k0 = 0; k0 < K; k0 += 64) {
#pragma unroll
    for (int it = 0; it < 4; ++it) {
      const int c = wid * 4 + it;
      const int row = c * 8 + lrow;
      GLDS16(A  + (size_t)(m0 + row) * K + k0 + lseg, sA + c * 512);
      GLDS16(BT + (size_t)(n0 + row) * K + k0 + lseg, sB + c * 512);
    }
    __syncthreads();
#pragma unroll
    for (int kk = 0; kk < 64; kk += 32) {
      bf16x8 af[4], bfv[4];
#pragma unroll
      for (int i = 0; i < 4; ++i)
        af[i] = *(const bf16x8*)(sA + (wm + i * 16 + fr) * 64 + kk + 8 * fq);
#pragma unroll
      for (int j = 0; j < 4; ++j)
        bfv[j] = *(const bf16x8*)(sB + (wn + j * 16 + fr) * 64 + kk + 8 * fq);
#pragma unroll
      for (int i = 0; i < 4; ++i)
#pragma unroll
        for (int j = 0; j < 4; ++j)
          acc[i][j] = __builtin_amdgcn_mfma_f32_16x16x32_bf16(af[i], bfv[j],
                                                              acc[i][j], 0, 0, 0);
    }
    __syncthreads();
  }

#pragma unroll
  for (int i = 0; i < 4; ++i) {
    const int grow = m0 + wm + i * 16 + fq * 4;
#pragma unroll
    for (int j = 0; j < 4; ++j) {
      const int gcol = n0 + wn + j * 16 + fr;
      const float bc = bias[gcol];
      if constexpr (EPI == 3) {
        if (gcol >= 2048) {  // V part -> transposed, wave-uniform branch
          bf16x4v pk;
#pragma unroll
          for (int r = 0; r < 4; ++r) pk[r] = (bf16)(acc[i][j][r] + bc);
          const size_t dd = (size_t)((grow >> 11) * 1024 + (gcol - 2048));
          *(bf16x4v*)(vout + dd * 2048 + (grow & 2047)) = pk;
          continue;
        }
      }
#pragma unroll
      for (int r = 0; r < 4; ++r) {
        const size_t idx = (size_t)(grow + r) * N + gcol;
        const float v = acc[i][j][r] + bc;
        if constexpr (EPI == 0 || EPI == 3) {
          ((bf16*)Cout)[idx] = (bf16)v;
        } else if constexpr (EPI == 1) {
          ((float*)Cout)[idx] = v + res[idx];
        } else {
          const float gg = (float)gbuf[idx];
          ((bf16*)Cout)[idx] = (bf16)(v * gg / (1.f + __expf(-gg)));
        }
      }
    }
  }
}

// ---------------------------------------------------------------------------
// MFMA windowed attention.  One block per (b*H+h, 64-query tile), 4 waves.
// Stage: Q[64][64] (stride 72), K[320][64] (stride 72), VT[64][320] (stride
// 328), all padded so frag reads are ~2-way bank aliases (byte stride == 16
// mod 128).  Wave w owns queries [16w,16w+16).
// S = Q K^T (20 j-frags x 2 k-steps), in-register softmax with band mask,
// P -> LDS bf16 (stride 328), PV = P @ V (10 k-steps x 4 j-frags).
// Stage base tS = clamp(qs0-128, 0, 2048-320): covers every in-band key.
// ---------------------------------------------------------------------------
__global__ __launch_bounds__(256) void attn_mfma(const bf16* __restrict__ qkv,
                                                 const bf16* __restrict__ vT,
                                                 bf16* __restrict__ ctx) {
  __shared__ bf16 sQ[64 * 72];
  __shared__ bf16 sK[320 * 72];
  __shared__ bf16 sVT[64 * 328];
  __shared__ bf16 sP[64 * 328];
  const int bh = blockIdx.x;
  const int b = bh >> 4, h = bh & 15;
  const int qs0 = blockIdx.y * 64;
  const int t0 = qs0 - 128;
  const int tS = t0 < 0 ? 0 : (t0 > S_LEN - 320 ? S_LEN - 320 : t0);
  const int tid = threadIdx.x, wid = tid >> 6, lane = tid & 63;
  const size_t bbase = (size_t)b * S_LEN;

  // ---- stage K (320x64) and Q (64x64) from qkv; VT (64x320) from vT ----
#pragma unroll
  for (int i = 0; i < 10; ++i) {
    const int c = i * 256 + tid, row = c >> 3, seg = (c & 7) * 8;
    *(bf16x8*)(sK + row * 72 + seg) =
        *(const bf16x8*)(qkv + (bbase + tS + row) * NQKV + 1024 + h * 64 + seg);
  }
#pragma unroll
  for (int i = 0; i < 2; ++i) {
    const int c = i * 256 + tid, row = c >> 3, seg = (c & 7) * 8;
    *(bf16x8*)(sQ + row * 72 + seg) =
        *(const bf16x8*)(qkv + (bbase + qs0 + row) * NQKV + h * 64 + seg);
  }
  {
    const int row = tid >> 2;
    const size_t vbase = ((size_t)bh * 64 + row) * 2048 + tS;
#pragma unroll
    for (int i = 0; i < 10; ++i) {
      const int seg = ((tid & 3) + 4 * i) * 8;
      *(bf16x8*)(sVT + row * 328 + seg) = *(const bf16x8*)(vT + vbase + seg);
    }
  }
  __syncthreads();

  const int fr = lane & 15, fq = lane >> 4;

  // ---- S = Q K^T : per wave 16 queries x 320 keys ----
  f32x4 s[20];
#pragma unroll
  for (int j = 0; j < 20; ++j) s[j] = f32x4{0.f, 0.f, 0.f, 0.f};
#pragma unroll
  for (int kk = 0; kk < 64; kk += 32) {
    const bf16x8 aq = *(const bf16x8*)(sQ + (wid * 16 + fr) * 72 + kk + 8 * fq);
#pragma unroll
    for (int j = 0; j < 20; ++j) {
      const bf16x8 bk = *(const bf16x8*)(sK + (j * 16 + fr) * 72 + kk + 8 * fq);
      s[j] = __builtin_amdgcn_mfma_f32_16x16x32_bf16(aq, bk, s[j], 0, 0, 0);
    }
  }

  // ---- softmax (band mask |q-t|<=128), C/D layout: row=fq*4+r, col=fr ----
#pragma unroll
  for (int r = 0; r < 4; ++r) {
    const int q_g = qs0 + wid * 16 + fq * 4 + r;
    float m = -1e30f;
#pragma unroll
    for (int j = 0; j < 20; ++j) {
      const int t_g = tS + j * 16 + fr;
      const bool ok = (unsigned)(q_g - t_g + 128) <= 256u;
      const float val = ok ? s[j][r] * 0.125f : -1e30f;
      s[j][r] = val;
      m = fmaxf(m, val);
    }
#pragma unroll
    for (int off = 1; off < 16; off <<= 1) m = fmaxf(m, __shfl_xor(m, off));
    float sm = 0.f;
#pragma unroll
    for (int j = 0; j < 20; ++j) {
      const float p = __expf(s[j][r] - m);
      s[j][r] = p;
      sm += p;
    }
#pragma unroll
    for (int off = 1; off < 16; off <<= 1) sm += __shfl_xor(sm, off);
    const float inv = 1.f / sm;
#pragma unroll
    for (int j = 0; j < 20; ++j)
      sP[(wid * 16 + fq * 4 + r) * 328 + j * 16 + fr] = (bf16)(s[j][r] * inv);
  }
  __syncthreads();

  // ---- O = P V : per wave 16 queries x 64 dims, K=320 ----
  f32x4 o[4];
#pragma unroll
  for (int j = 0; j < 4; ++j) o[j] = f32x4{0.f, 0.f, 0.f, 0.f};
#pragma unroll
  for (int ks = 0; ks < 10; ++ks) {
    const int kk = ks * 32;
    const bf16x8 pa = *(const bf16x8*)(sP + (wid * 16 + fr) * 328 + kk + 8 * fq);
#pragma unroll
    for (int j = 0; j < 4; ++j) {
      const bf16x8 vb = *(const bf16x8*)(sVT + (j * 16 + fr) * 328 + kk + 8 * fq);
      o[j] = __builtin_amdgcn_mfma_f32_16x16x32_bf16(pa, vb, o[j], 0, 0, 0);
    }
  }
#pragma unroll
  for (int j = 0; j < 4; ++j)
#pragma unroll
    for (int r = 0; r < 4; ++r) {
      const int q = qs0 + wid * 16 + fq * 4 + r;
      ctx[(bbase + q) * 1024 + h * 64 + j * 16 + fr] = (bf16)o[j][r];
    }
}

// ---------------------------------------------------------------------------
extern "C" void kernel_launch(void* const* d_in, const int* in_sizes, int n_in,
                              void* d_out, int out_size, void* d_ws, size_t ws_size,
                              hipStream_t stream) {
  const float* x    = (const float*)d_in[0];
  const float* ln1w = (const float*)d_in[2];
  const float* ln1b = (const float*)d_in[3];
  const float* Wq   = (const float*)d_in[4];
  const float* bq   = (const float*)d_in[5];
  const float* Wk   = (const float*)d_in[6];
  const float* bk   = (const float*)d_in[7];
  const float* Wv   = (const float*)d_in[8];
  const float* bv   = (const float*)d_in[9];
  const float* Wo   = (const float*)d_in[10];
  const float* bo   = (const float*)d_in[11];
  const float* ln2w = (const float*)d_in[12];
  const float* ln2b = (const float*)d_in[13];
  const float* Wg   = (const float*)d_in[14];
  const float* bg   = (const float*)d_in[15];
  const float* Wu   = (const float*)d_in[16];
  const float* bu   = (const float*)d_in[17];
  const float* Wd   = (const float*)d_in[18];
  const float* bd   = (const float*)d_in[19];

  char* ws = (char*)d_ws;
  size_t off = 0;
  auto take = [&](size_t bytes) {
    char* p = ws + off;
    off += (bytes + 255) & ~(size_t)255;
    return p;
  };
  bf16*  wqkvT = (bf16*)take((size_t)3072 * 1024 * 2);
  bf16*  woT   = (bf16*)take((size_t)1024 * 1024 * 2);
  bf16*  wgT   = (bf16*)take((size_t)4096 * 1024 * 2);
  bf16*  wuT   = (bf16*)take((size_t)4096 * 1024 * 2);
  bf16*  wdT   = (bf16*)take((size_t)1024 * 4096 * 2);
  float* bqkv  = (float*)take((size_t)3072 * 4);
  bf16*  h     = (bf16*)take((size_t)4096 * 1024 * 2);
  bf16*  qkv   = (bf16*)take((size_t)4096 * 3072 * 2);   // Q|K cols, V unused
  bf16*  ctx   = (bf16*)take((size_t)4096 * 1024 * 2);
  bf16*  vT    = (bf16*)take((size_t)2048 * 2048 * 2);   // [B*H*64][2048]
  float* x1    = (float*)take((size_t)4096 * 1024 * 4);
  bf16*  h2    = (bf16*)take((size_t)4096 * 1024 * 2);
  bf16*  gated = (bf16*)take((size_t)4096 * 4096 * 2);
  bf16*  g     = (bf16*)qkv;                             // alias qkv+ctx (32MB, dead by then)
  (void)ws_size; (void)in_sizes; (void)n_in; (void)out_size;

  const dim3 tb(32, 8);
  tr_cast<<<dim3(32, 32), tb, 0, stream>>>(Wq, wqkvT, 1024, 1024);
  tr_cast<<<dim3(32, 32), tb, 0, stream>>>(Wk, wqkvT + (size_t)1024 * 1024, 1024, 1024);
  tr_cast<<<dim3(32, 32), tb, 0, stream>>>(Wv, wqkvT + (size_t)2048 * 1024, 1024, 1024);
  tr_cast<<<dim3(32, 32), tb, 0, stream>>>(Wo, woT, 1024, 1024);
  tr_cast<<<dim3(128, 32), tb, 0, stream>>>(Wg, wgT, 1024, 4096);
  tr_cast<<<dim3(128, 32), tb, 0, stream>>>(Wu, wuT, 1024, 4096);
  tr_cast<<<dim3(32, 128), tb, 0, stream>>>(Wd, wdT, 4096, 1024);
  concat3<<<12, 256, 0, stream>>>(bq, bk, bv, bqkv);

  // LN1 -> h
  ln_bf16<<<4096, 256, 0, stream>>>(x, ln1w, ln1b, h);
  // QKV: Q|K -> qkv bf16, V -> vT transposed
  gemm_bf16t<3><<<dim3(24, 32), 256, 0, stream>>>(h, wqkvT, bqkv, nullptr, nullptr,
                                                  vT, qkv, 4096, 3072, 1024);
  // windowed attention -> ctx bf16
  attn_mfma<<<dim3(32, 32), 256, 0, stream>>>(qkv, vT, ctx);
  // x1 = x + ctx @ Wo + bo
  gemm_bf16t<1><<<dim3(8, 32), 256, 0, stream>>>(ctx, woT, bo, x, nullptr, nullptr,
                                                 x1, 4096, 1024, 1024);
  // LN2 -> h2
  ln_bf16<<<4096, 256, 0, stream>>>(x1, ln2w, ln2b, h2);
  // g = h2 @ Wg + bg (bf16)
  gemm_bf16t<0><<<dim3(32, 32), 256, 0, stream>>>(h2, wgT, bg, nullptr, nullptr, nullptr,
                                                  g, 4096, 4096, 1024);
  // gated = silu(g) * (h2 @ Wu + bu)  (bf16)
  gemm_bf16t<2><<<dim3(32, 32), 256, 0, stream>>>(h2, wuT, bu, nullptr, g, nullptr,
                                                  gated, 4096, 4096, 1024);
  // out = x1 + gated @ Wd + bd  (fp32)
  gemm_bf16t<1><<<dim3(8, 32), 256, 0, stream>>>(gated, wdT, bd, x1, nullptr, nullptr,
                                                 d_out, 4096, 1024, 4096);
}

// Round 4
// 311.856 us; speedup vs baseline: 1.9792x; 1.1155x over previous
//
#include <hip/hip_runtime.h>
#include <stdint.h>

// ---------------------------------------------------------------------------
// WindowedSelfAttentionLayer: B=2 S=2048 D=1024 H=16 DH=64 HID=4096 WIN=256
//  - gemm256: 256x256-tile, 8-wave, BK=64, RACE-FREE 2-phase double-buffer
//    (stage next tile into other parity, __syncthreads per tile).  T1 XCD
//    swizzle.  EPI1 = QKV (Q|K + V-transposed), EPI2 = fused SwiGLU.
//  - gemm_bf16t: m97-style 128x128 kernel for N=1024 GEMMs (Wo, Wd).
//  - attn_mfma: MFMA flash-style windowed attention.
// ---------------------------------------------------------------------------

typedef __bf16 bf16;
typedef bf16  bf16x8 __attribute__((ext_vector_type(8)));
typedef bf16  bf16x4v __attribute__((ext_vector_type(4)));
typedef float f32x4  __attribute__((ext_vector_type(4)));

#define S_LEN 2048

#define GLDS16(gp, lp)                                                          \
  __builtin_amdgcn_global_load_lds(                                            \
      (__attribute__((address_space(1))) void*)(gp),                            \
      (__attribute__((address_space(3))) void*)(lp), 16, 0, 0)

// ---------------------------------------------------------------------------
// LayerNorm (fp32 in) -> bf16 out.  One block (256 thr) per 1024-dim row.
// ---------------------------------------------------------------------------
__global__ __launch_bounds__(256) void ln_bf16(const float* __restrict__ x,
                                               const float* __restrict__ w,
                                               const float* __restrict__ bb,
                                               bf16* __restrict__ out) {
  const int row = blockIdx.x, tid = threadIdx.x;
  const int wid = tid >> 6, lane = tid & 63;
  const float4 v = ((const float4*)(x + (size_t)row * 1024))[tid];
  float s = v.x + v.y + v.z + v.w;
  float q = v.x * v.x + v.y * v.y + v.z * v.z + v.w * v.w;
#pragma unroll
  for (int off = 32; off > 0; off >>= 1) {
    s += __shfl_xor(s, off);
    q += __shfl_xor(q, off);
  }
  __shared__ float rs_[4], rq_[4];
  if (lane == 0) { rs_[wid] = s; rq_[wid] = q; }
  __syncthreads();
  s = rs_[0] + rs_[1] + rs_[2] + rs_[3];
  q = rq_[0] + rq_[1] + rq_[2] + rq_[3];
  const float mean = s * (1.f / 1024.f);
  const float var  = q * (1.f / 1024.f) - mean * mean;
  const float rstd = rsqrtf(var + 1e-5f);
  const float4 wv = ((const float4*)w)[tid];
  const float4 bv = ((const float4*)bb)[tid];
  bf16x4v o;
  o[0] = (bf16)((v.x - mean) * rstd * wv.x + bv.x);
  o[1] = (bf16)((v.y - mean) * rstd * wv.y + bv.y);
  o[2] = (bf16)((v.z - mean) * rstd * wv.z + bv.z);
  o[3] = (bf16)((v.w - mean) * rstd * wv.w + bv.w);
  ((bf16x4v*)(out + (size_t)row * 1024))[tid] = o;
}

// ---------------------------------------------------------------------------
// Transpose + cast: in fp32 [R][C] -> out bf16 [C][R].
// ---------------------------------------------------------------------------
__global__ __launch_bounds__(256) void tr_cast(const float* __restrict__ in,
                                               bf16* __restrict__ out, int R, int C) {
  __shared__ float t[32][33];
  const int tx = threadIdx.x, ty = threadIdx.y;
  const int r0 = blockIdx.y * 32, c0 = blockIdx.x * 32;
#pragma unroll
  for (int i = 0; i < 4; ++i)
    t[ty + 8 * i][tx] = in[(size_t)(r0 + ty + 8 * i) * C + c0 + tx];
  __syncthreads();
#pragma unroll
  for (int i = 0; i < 4; ++i)
    out[(size_t)(c0 + ty + 8 * i) * R + r0 + tx] = (bf16)t[tx][ty + 8 * i];
}

__global__ void concat3(const float* __restrict__ a, const float* __restrict__ b,
                        const float* __restrict__ c, float* __restrict__ o) {
  int i = blockIdx.x * 256 + threadIdx.x;
  if (i < 1024) o[i] = a[i];
  else if (i < 2048) o[i] = b[i - 1024];
  else if (i < 3072) o[i] = c[i - 2048];
}

// ---------------------------------------------------------------------------
// 256x256 2-phase GEMM, 512 threads = 8 waves (2M x 4N), BK=64.
// Per wave: 128x64 output = 8x4 frags.  LDS: E/O double buffer, linear
// row-major [256][64] bf16 per matrix per parity (128 KB total).
// Schedule per K-tile: STAGE(other parity, kt+1) -> ds_read+MFMA(cur) ->
// __syncthreads (implicit vmcnt(0)+lgkmcnt(0) drain => no LDS races).
// EPI 1: QKV -> Q|K bf16 [4096][2048] + V transposed into vT.
// EPI 2: fused SwiGLU: B rows 0-127 = WgT, rows 128-255 = WuT (tile = 128
//        out cols); epilogue swaps u through LDS, writes silu(g)*u bf16.
// ---------------------------------------------------------------------------
template <int EPI>  // 1 = QKV, 2 = fused SwiGLU
__global__ __launch_bounds__(512, 2) void gemm256(
    const bf16* __restrict__ A, const bf16* __restrict__ BT,
    const bf16* __restrict__ BT2, const float* __restrict__ bias,
    const float* __restrict__ bias2, bf16* __restrict__ outp,
    bf16* __restrict__ vout, int K) {
  __shared__ char smem[131072];
  char* AbufE = smem;
  char* AbufO = smem + 32768;
  char* BbufE = smem + 65536;
  char* BbufO = smem + 98304;

  const int tid = threadIdx.x, wid = tid >> 6, lane = tid & 63;
  const int fr = lane & 15, fq = lane >> 4;
  const int wm = (wid >> 2) * 128, wn = (wid & 3) * 64;

  // T1: bijective XCD swizzle
  const int nwg = gridDim.x;
  int wg = blockIdx.x;
  {
    int qq = nwg >> 3, rr = nwg & 7, xc = wg & 7, ix = wg >> 3;
    wg = (xc < rr ? xc * (qq + 1) : rr * (qq + 1) + (xc - rr) * qq) + ix;
  }
  const int mtile = wg & 15, ntile = wg >> 4;
  const int m0 = mtile * 256;
  const int nbase = (EPI == 2) ? ntile * 128 : ntile * 256;

  // staging source pointers (linear, 16B/lane; dst rows 64q + wid*8 + lane/8)
  const int srow = wid * 8 + (lane >> 3);
  const int sseg = (lane & 7) * 8;
  const bf16* srcB1 = (EPI == 2) ? BT2 : BT;
  const int rB1 = (EPI == 2) ? nbase : nbase + 128;
  const bf16* pA  = A + (size_t)(m0 + srow) * K + sseg;
  const bf16* pBl = BT + (size_t)(nbase + srow) * K + sseg;
  const bf16* pBh = srcB1 + (size_t)(rB1 + srow) * K + sseg;
  const size_t K64 = (size_t)64 * K;
  char* dA = (char*)0;  // set per STAGE via parity
  char* dB = (char*)0;

  auto STAGE = [&](char* ab, char* bb, size_t koff) {
    GLDS16(pA + koff,            ab + wid * 1024);
    GLDS16(pA + K64 + koff,      ab + 8192 + wid * 1024);
    GLDS16(pA + 2 * K64 + koff,  ab + 16384 + wid * 1024);
    GLDS16(pA + 3 * K64 + koff,  ab + 24576 + wid * 1024);
    GLDS16(pBl + koff,           bb + wid * 1024);
    GLDS16(pBl + K64 + koff,     bb + 8192 + wid * 1024);
    GLDS16(pBh + koff,           bb + 16384 + wid * 1024);
    GLDS16(pBh + K64 + koff,     bb + 24576 + wid * 1024);
  };

  f32x4 acc[8][4];
#pragma unroll
  for (int i = 0; i < 8; ++i)
#pragma unroll
    for (int j = 0; j < 4; ++j) acc[i][j] = f32x4{0.f, 0.f, 0.f, 0.f};

  const int aOff = (wm + fr) * 128 + fq * 16;
  const int bOff = (wn + fr) * 128 + fq * 16;

  auto COMPUTE = [&](const char* ab, const char* bb) {
#pragma unroll
    for (int kh = 0; kh < 2; ++kh) {
      const int kb = kh * 64;
      bf16x8 av[8], bv[4];
#pragma unroll
      for (int mi = 0; mi < 8; ++mi)
        av[mi] = *(const bf16x8*)(ab + aOff + mi * 2048 + kb);
#pragma unroll
      for (int nj = 0; nj < 4; ++nj)
        bv[nj] = *(const bf16x8*)(bb + bOff + nj * 2048 + kb);
#pragma unroll
      for (int mi = 0; mi < 8; ++mi)
#pragma unroll
        for (int nj = 0; nj < 4; ++nj)
          acc[mi][nj] = __builtin_amdgcn_mfma_f32_16x16x32_bf16(
              av[mi], bv[nj], acc[mi][nj], 0, 0, 0);
    }
  };

  // prologue
  STAGE(AbufE, BbufE, 0);
  __syncthreads();

  const int NT = K >> 6;  // even in all uses (16 or 64)
  for (int kt = 0; kt < NT; kt += 2) {
    const size_t k1 = (size_t)(kt + 1) << 6;
    const size_t k2 = (size_t)(kt + 2) << 6;
    if (kt + 1 < NT) STAGE(AbufO, BbufO, k1);
    COMPUTE(AbufE, BbufE);
    __syncthreads();
    if (kt + 1 < NT) {
      if (kt + 2 < NT) STAGE(AbufE, BbufE, k2);
      COMPUTE(AbufO, BbufO);
      __syncthreads();
    }
  }

  if constexpr (EPI == 1) {
    if (nbase < 2048) {  // Q|K -> [4096][2048]
#pragma unroll
      for (int mi = 0; mi < 8; ++mi)
#pragma unroll
        for (int nj = 0; nj < 4; ++nj) {
          const int grow = m0 + wm + mi * 16 + fq * 4;
          const int gcol = nbase + wn + nj * 16 + fr;
          const float bc = bias[gcol];
#pragma unroll
          for (int r = 0; r < 4; ++r)
            outp[(size_t)(grow + r) * 2048 + gcol] = (bf16)(acc[mi][nj][r] + bc);
        }
    } else {  // V -> vT[(b*1024+d)][t], 4 consecutive t packed
#pragma unroll
      for (int mi = 0; mi < 8; ++mi)
#pragma unroll
        for (int nj = 0; nj < 4; ++nj) {
          const int grow = m0 + wm + mi * 16 + fq * 4;
          const int gcol = nbase + wn + nj * 16 + fr;
          const float bc = bias[gcol];
          bf16x4v pk;
#pragma unroll
          for (int r = 0; r < 4; ++r) pk[r] = (bf16)(acc[mi][nj][r] + bc);
          *(bf16x4v*)(vout + ((size_t)((grow >> 11) * 1024 + (gcol - 2048))) * 2048 +
                      (grow & 2047)) = pk;
        }
    }
  } else {  // EPI 2: fused silu(g)*u  (B rows 0-127 = g cols, 128-255 = u cols)
    __syncthreads();
    float* uls = (float*)smem;  // [256][128] fp32 = 128 KB
    if (wn >= 128) {            // u-half waves: deposit u+bias
#pragma unroll
      for (int mi = 0; mi < 8; ++mi)
#pragma unroll
        for (int nj = 0; nj < 4; ++nj) {
          const int rowL = wm + mi * 16 + fq * 4;
          const int cu = wn - 128 + nj * 16 + fr;
          const float bc = bias2[nbase + cu];
#pragma unroll
          for (int r = 0; r < 4; ++r)
            uls[(rowL + r) * 128 + cu] = acc[mi][nj][r] + bc;
        }
    }
    __syncthreads();
    if (wn < 128) {             // g-half waves: silu(g)*u -> out
#pragma unroll
      for (int mi = 0; mi < 8; ++mi)
#pragma unroll
        for (int nj = 0; nj < 4; ++nj) {
          const int rowL = wm + mi * 16 + fq * 4;
          const int cg = wn + nj * 16 + fr;
          const float bc = bias[nbase + cg];
#pragma unroll
          for (int r = 0; r < 4; ++r) {
            const float g = acc[mi][nj][r] + bc;
            const float u = uls[(rowL + r) * 128 + cg];
            outp[(size_t)(m0 + rowL + r) * 4096 + nbase + cg] =
                (bf16)(g * u / (1.f + __expf(-g)));
          }
        }
    }
  }
}

// ---------------------------------------------------------------------------
// m97-style 128x128 GEMM (N=1024: Wo, Wd).  EPI 1: fp32 out + residual.
// ---------------------------------------------------------------------------
template <int EPI>
__global__ __launch_bounds__(256) void gemm_bf16t(
    const bf16* __restrict__ A, const bf16* __restrict__ BT,
    const float* __restrict__ bias, const float* __restrict__ res,
    void* __restrict__ Cout, int M, int N, int K) {
  __shared__ bf16 sA[128 * 64];
  __shared__ bf16 sB[128 * 64];
  const int tid = threadIdx.x;
  const int wid = tid >> 6, lane = tid & 63;
  const int m0 = blockIdx.y * 128, n0 = blockIdx.x * 128;
  const int wm = (wid >> 1) * 64, wn = (wid & 1) * 64;
  const int lrow = lane >> 3, lseg = (lane & 7) * 8;
  const int fr = lane & 15, fq = lane >> 4;

  f32x4 acc[4][4];
#pragma unroll
  for (int i = 0; i < 4; ++i)
#pragma unroll
    for (int j = 0; j < 4; ++j) acc[i][j] = f32x4{0.f, 0.f, 0.f, 0.f};

  for (int k0 = 0; k0 < K; k0 += 64) {
#pragma unroll
    for (int it = 0; it < 4; ++it) {
      const int c = wid * 4 + it;
      const int row = c * 8 + lrow;
      GLDS16(A  + (size_t)(m0 + row) * K + k0 + lseg, sA + c * 512);
      GLDS16(BT + (size_t)(n0 + row) * K + k0 + lseg, sB + c * 512);
    }
    __syncthreads();
#pragma unroll
    for (int kk = 0; kk < 64; kk += 32) {
      bf16x8 af[4], bfv[4];
#pragma unroll
      for (int i = 0; i < 4; ++i)
        af[i] = *(const bf16x8*)(sA + (wm + i * 16 + fr) * 64 + kk + 8 * fq);
#pragma unroll
      for (int j = 0; j < 4; ++j)
        bfv[j] = *(const bf16x8*)(sB + (wn + j * 16 + fr) * 64 + kk + 8 * fq);
#pragma unroll
      for (int i = 0; i < 4; ++i)
#pragma unroll
        for (int j = 0; j < 4; ++j)
          acc[i][j] = __builtin_amdgcn_mfma_f32_16x16x32_bf16(af[i], bfv[j],
                                                              acc[i][j], 0, 0, 0);
    }
    __syncthreads();
  }

#pragma unroll
  for (int i = 0; i < 4; ++i) {
    const int grow = m0 + wm + i * 16 + fq * 4;
#pragma unroll
    for (int j = 0; j < 4; ++j) {
      const int gcol = n0 + wn + j * 16 + fr;
      const float bc = bias[gcol];
#pragma unroll
      for (int r = 0; r < 4; ++r) {
        const size_t idx = (size_t)(grow + r) * N + gcol;
        const float v = acc[i][j][r] + bc;
        if constexpr (EPI == 1) {
          ((float*)Cout)[idx] = v + res[idx];
        } else {
          ((bf16*)Cout)[idx] = (bf16)v;
        }
      }
    }
  }
}

// ---------------------------------------------------------------------------
// MFMA windowed attention (qk stride 2048: Q at +0, K at +1024).
// ---------------------------------------------------------------------------
__global__ __launch_bounds__(256) void attn_mfma(const bf16* __restrict__ qk,
                                                 const bf16* __restrict__ vT,
                                                 bf16* __restrict__ ctx) {
  __shared__ bf16 sQ[64 * 72];
  __shared__ bf16 sK[320 * 72];
  __shared__ bf16 sVT[64 * 328];
  __shared__ bf16 sP[64 * 328];
  const int bh = blockIdx.x;
  const int b = bh >> 4, h = bh & 15;
  const int qs0 = blockIdx.y * 64;
  const int t0 = qs0 - 128;
  const int tS = t0 < 0 ? 0 : (t0 > S_LEN - 320 ? S_LEN - 320 : t0);
  const int tid = threadIdx.x, wid = tid >> 6, lane = tid & 63;
  const size_t bbase = (size_t)b * S_LEN;

#pragma unroll
  for (int i = 0; i < 10; ++i) {
    const int c = i * 256 + tid, row = c >> 3, seg = (c & 7) * 8;
    *(bf16x8*)(sK + row * 72 + seg) =
        *(const bf16x8*)(qk + (bbase + tS + row) * 2048 + 1024 + h * 64 + seg);
  }
#pragma unroll
  for (int i = 0; i < 2; ++i) {
    const int c = i * 256 + tid, row = c >> 3, seg = (c & 7) * 8;
    *(bf16x8*)(sQ + row * 72 + seg) =
        *(const bf16x8*)(qk + (bbase + qs0 + row) * 2048 + h * 64 + seg);
  }
  {
    const int row = tid >> 2;
    const size_t vbase = ((size_t)bh * 64 + row) * 2048 + tS;
#pragma unroll
    for (int i = 0; i < 10; ++i) {
      const int seg = ((tid & 3) + 4 * i) * 8;
      *(bf16x8*)(sVT + row * 328 + seg) = *(const bf16x8*)(vT + vbase + seg);
    }
  }
  __syncthreads();

  const int fr = lane & 15, fq = lane >> 4;

  f32x4 s[20];
#pragma unroll
  for (int j = 0; j < 20; ++j) s[j] = f32x4{0.f, 0.f, 0.f, 0.f};
#pragma unroll
  for (int kk = 0; kk < 64; kk += 32) {
    const bf16x8 aq = *(const bf16x8*)(sQ + (wid * 16 + fr) * 72 + kk + 8 * fq);
#pragma unroll
    for (int j = 0; j < 20; ++j) {
      const bf16x8 bk = *(const bf16x8*)(sK + (j * 16 + fr) * 72 + kk + 8 * fq);
      s[j] = __builtin_amdgcn_mfma_f32_16x16x32_bf16(aq, bk, s[j], 0, 0, 0);
    }
  }

#pragma unroll
  for (int r = 0; r < 4; ++r) {
    const int q_g = qs0 + wid * 16 + fq * 4 + r;
    float m = -1e30f;
#pragma unroll
    for (int j = 0; j < 20; ++j) {
      const int t_g = tS + j * 16 + fr;
      const bool ok = (unsigned)(q_g - t_g + 128) <= 256u;
      const float val = ok ? s[j][r] * 0.125f : -1e30f;
      s[j][r] = val;
      m = fmaxf(m, val);
    }
#pragma unroll
    for (int off = 1; off < 16; off <<= 1) m = fmaxf(m, __shfl_xor(m, off));
    float sm = 0.f;
#pragma unroll
    for (int j = 0; j < 20; ++j) {
      const float p = __expf(s[j][r] - m);
      s[j][r] = p;
      sm += p;
    }
#pragma unroll
    for (int off = 1; off < 16; off <<= 1) sm += __shfl_xor(sm, off);
    const float inv = 1.f / sm;
#pragma unroll
    for (int j = 0; j < 20; ++j)
      sP[(wid * 16 + fq * 4 + r) * 328 + j * 16 + fr] = (bf16)(s[j][r] * inv);
  }
  __syncthreads();

  f32x4 o[4];
#pragma unroll
  for (int j = 0; j < 4; ++j) o[j] = f32x4{0.f, 0.f, 0.f, 0.f};
#pragma unroll
  for (int ks = 0; ks < 10; ++ks) {
    const int kk = ks * 32;
    const bf16x8 pa = *(const bf16x8*)(sP + (wid * 16 + fr) * 328 + kk + 8 * fq);
#pragma unroll
    for (int j = 0; j < 4; ++j) {
      const bf16x8 vb = *(const bf16x8*)(sVT + (j * 16 + fr) * 328 + kk + 8 * fq);
      o[j] = __builtin_amdgcn_mfma_f32_16x16x32_bf16(pa, vb, o[j], 0, 0, 0);
    }
  }
#pragma unroll
  for (int j = 0; j < 4; ++j)
#pragma unroll
    for (int r = 0; r < 4; ++r) {
      const int q = qs0 + wid * 16 + fq * 4 + r;
      ctx[(bbase + q) * 1024 + h * 64 + j * 16 + fr] = (bf16)o[j][r];
    }
}

// ---------------------------------------------------------------------------
extern "C" void kernel_launch(void* const* d_in, const int* in_sizes, int n_in,
                              void* d_out, int out_size, void* d_ws, size_t ws_size,
                              hipStream_t stream) {
  const float* x    = (const float*)d_in[0];
  const float* ln1w = (const float*)d_in[2];
  const float* ln1b = (const float*)d_in[3];
  const float* Wq   = (const float*)d_in[4];
  const float* bq   = (const float*)d_in[5];
  const float* Wk   = (const float*)d_in[6];
  const float* bk   = (const float*)d_in[7];
  const float* Wv   = (const float*)d_in[8];
  const float* bv   = (const float*)d_in[9];
  const float* Wo   = (const float*)d_in[10];
  const float* bo   = (const float*)d_in[11];
  const float* ln2w = (const float*)d_in[12];
  const float* ln2b = (const float*)d_in[13];
  const float* Wg   = (const float*)d_in[14];
  const float* bg   = (const float*)d_in[15];
  const float* Wu   = (const float*)d_in[16];
  const float* bu   = (const float*)d_in[17];
  const float* Wd   = (const float*)d_in[18];
  const float* bd   = (const float*)d_in[19];

  char* ws = (char*)d_ws;
  size_t off = 0;
  auto take = [&](size_t bytes) {
    char* p = ws + off;
    off += (bytes + 255) & ~(size_t)255;
    return p;
  };
  bf16*  wqkvT = (bf16*)take((size_t)3072 * 1024 * 2);
  bf16*  woT   = (bf16*)take((size_t)1024 * 1024 * 2);
  bf16*  wgT   = (bf16*)take((size_t)4096 * 1024 * 2);
  bf16*  wuT   = (bf16*)take((size_t)4096 * 1024 * 2);
  bf16*  wdT   = (bf16*)take((size_t)1024 * 4096 * 2);
  float* bqkv  = (float*)take((size_t)3072 * 4);
  bf16*  h     = (bf16*)take((size_t)4096 * 1024 * 2);
  bf16*  qk    = (bf16*)take((size_t)4096 * 2048 * 2);   // Q|K
  bf16*  ctx   = (bf16*)take((size_t)4096 * 1024 * 2);
  bf16*  vT    = (bf16*)take((size_t)2048 * 2048 * 2);   // [B*H*64][2048]
  float* x1    = (float*)take((size_t)4096 * 1024 * 4);
  bf16*  h2    = (bf16*)take((size_t)4096 * 1024 * 2);
  bf16*  gated = (bf16*)take((size_t)4096 * 4096 * 2);
  (void)ws_size; (void)in_sizes; (void)n_in; (void)out_size;

  const dim3 tb(32, 8);
  tr_cast<<<dim3(32, 32), tb, 0, stream>>>(Wq, wqkvT, 1024, 1024);
  tr_cast<<<dim3(32, 32), tb, 0, stream>>>(Wk, wqkvT + (size_t)1024 * 1024, 1024, 1024);
  tr_cast<<<dim3(32, 32), tb, 0, stream>>>(Wv, wqkvT + (size_t)2048 * 1024, 1024, 1024);
  tr_cast<<<dim3(32, 32), tb, 0, stream>>>(Wo, woT, 1024, 1024);
  tr_cast<<<dim3(128, 32), tb, 0, stream>>>(Wg, wgT, 1024, 4096);
  tr_cast<<<dim3(128, 32), tb, 0, stream>>>(Wu, wuT, 1024, 4096);
  tr_cast<<<dim3(32, 128), tb, 0, stream>>>(Wd, wdT, 4096, 1024);
  concat3<<<12, 256, 0, stream>>>(bq, bk, bv, bqkv);

  // LN1 -> h
  ln_bf16<<<4096, 256, 0, stream>>>(x, ln1w, ln1b, h);
  // QKV: Q|K -> qk (stride 2048), V -> vT transposed.  grid 16 m x 12 n.
  gemm256<1><<<192, 512, 0, stream>>>(h, wqkvT, nullptr, bqkv, nullptr,
                                      qk, vT, 1024);
  // windowed attention -> ctx bf16
  attn_mfma<<<dim3(32, 32), 256, 0, stream>>>(qk, vT, ctx);
  // x1 = x + ctx @ Wo + bo
  gemm_bf16t<1><<<dim3(8, 32), 256, 0, stream>>>(ctx, woT, bo, x,
                                                 x1, 4096, 1024, 1024);
  // LN2 -> h2
  ln_bf16<<<4096, 256, 0, stream>>>(x1, ln2w, ln2b, h2);
  // gated = silu(h2@Wg+bg) * (h2@Wu+bu)   (fused, grid 16 m x 32 n-halves)
  gemm256<2><<<512, 512, 0, stream>>>(h2, wgT, wuT, bg, bu, gated, nullptr, 1024);
  // out = x1 + gated @ Wd + bd  (fp32)
  gemm_bf16t<1><<<dim3(8, 32), 256, 0, stream>>>(gated, wdT, bd, x1,
                                                 d_out, 4096, 1024, 4096);
}

// Round 6
// 265.760 us; speedup vs baseline: 2.3225x; 1.1734x over previous
//
#include <hip/hip_runtime.h>
#include <stdint.h>

// ---------------------------------------------------------------------------
// WindowedSelfAttentionLayer: B=2 S=2048 D=1024 H=16 HID=4096 WIN=256
//  - gemm256p: 256x256-tile, 8-wave, BK=64, K=1024/slice, 8-phase pipeline:
//    section-granular LDS recycling (WAR/RAW-safe by barrier ordering),
//    counted vmcnt(10), T2 3-bit XOR swizzle (pre-swizzled global source),
//    T5 setprio, T1 XCD swizzle.  EPI1=QKV, EPI2=fused SwiGLU,
//    EPI3=Wd split-K bf16 partials (4 x 8MB, aliased over dead buffers).
//  - gemm_bf16t: m97-style 128x128 kernel for Wo.
//  - attn_mfma: MFMA flash-style windowed attention.
// ---------------------------------------------------------------------------

typedef __bf16 bf16;
typedef bf16  bf16x8 __attribute__((ext_vector_type(8)));
typedef bf16  bf16x4v __attribute__((ext_vector_type(4)));
typedef float f32x4  __attribute__((ext_vector_type(4)));

#define S_LEN 2048

#define GLDS16(gp, lp)                                                          \
  __builtin_amdgcn_global_load_lds(                                            \
      (__attribute__((address_space(1))) void*)(gp),                            \
      (__attribute__((address_space(3))) void*)(lp), 16, 0, 0)

// ---------------------------------------------------------------------------
__global__ __launch_bounds__(256) void ln_bf16(const float* __restrict__ x,
                                               const float* __restrict__ w,
                                               const float* __restrict__ bb,
                                               bf16* __restrict__ out) {
  const int row = blockIdx.x, tid = threadIdx.x;
  const int wid = tid >> 6, lane = tid & 63;
  const float4 v = ((const float4*)(x + (size_t)row * 1024))[tid];
  float s = v.x + v.y + v.z + v.w;
  float q = v.x * v.x + v.y * v.y + v.z * v.z + v.w * v.w;
#pragma unroll
  for (int off = 32; off > 0; off >>= 1) {
    s += __shfl_xor(s, off);
    q += __shfl_xor(q, off);
  }
  __shared__ float rs_[4], rq_[4];
  if (lane == 0) { rs_[wid] = s; rq_[wid] = q; }
  __syncthreads();
  s = rs_[0] + rs_[1] + rs_[2] + rs_[3];
  q = rq_[0] + rq_[1] + rq_[2] + rq_[3];
  const float mean = s * (1.f / 1024.f);
  const float var  = q * (1.f / 1024.f) - mean * mean;
  const float rstd = rsqrtf(var + 1e-5f);
  const float4 wv = ((const float4*)w)[tid];
  const float4 bv = ((const float4*)bb)[tid];
  bf16x4v o;
  o[0] = (bf16)((v.x - mean) * rstd * wv.x + bv.x);
  o[1] = (bf16)((v.y - mean) * rstd * wv.y + bv.y);
  o[2] = (bf16)((v.z - mean) * rstd * wv.z + bv.z);
  o[3] = (bf16)((v.w - mean) * rstd * wv.w + bv.w);
  ((bf16x4v*)(out + (size_t)row * 1024))[tid] = o;
}

// ---------------------------------------------------------------------------
__global__ __launch_bounds__(256) void tr_cast(const float* __restrict__ in,
                                               bf16* __restrict__ out, int R, int C) {
  __shared__ float t[32][33];
  const int tx = threadIdx.x, ty = threadIdx.y;
  const int r0 = blockIdx.y * 32, c0 = blockIdx.x * 32;
#pragma unroll
  for (int i = 0; i < 4; ++i)
    t[ty + 8 * i][tx] = in[(size_t)(r0 + ty + 8 * i) * C + c0 + tx];
  __syncthreads();
#pragma unroll
  for (int i = 0; i < 4; ++i)
    out[(size_t)(c0 + ty + 8 * i) * R + r0 + tx] = (bf16)t[tx][ty + 8 * i];
}

__global__ void concat3(const float* __restrict__ a, const float* __restrict__ b,
                        const float* __restrict__ c, float* __restrict__ o) {
  int i = blockIdx.x * 256 + threadIdx.x;
  if (i < 1024) o[i] = a[i];
  else if (i < 2048) o[i] = b[i - 1024];
  else if (i < 3072) o[i] = c[i - 2048];
}

// ---------------------------------------------------------------------------
// 8-phase 256x256 GEMM, K=1024 per launch-slice (16 K-tiles), 512 thr =
// 8 waves (2M x 4N).  LDS (128KB): A[parity][sec][128rows][128B] + B same.
//   A sec a = tile rows {r:(r>>6)&1==a}, local = ((r>>7)<<6)|(r&63)
//   B sec b = tile cols {n:(n>>5)&1==b}, local = ((n>>6)<<5)|(n&31)
// Phase p of tile t reads (A_sec(p&1), B_sec(p>>1)) of parity t&1; computes
// quadrant acc[4a..4a+3][2b..2b+1].  Stage schedule (tile te even, to=te+1):
//   ph0:A1(te+1) ph1:B1(te+1) ph2:B0(te+2) ph3:A0(te+2)
//   ph4:A1(to+1) ph5:B1(to+1) ph6:B0(to+2) ph7:A0(to+2)
// vmcnt(10) at all phases except ph3/ph7 (none); every section drains
// exactly at (or before) its first reading phase; overwrites are issued
// only after the trailing barrier of the section's last reading phase.
// T2: stage source seg ^= (row&7); read col seg ^= (fr&7)  (involution).
// ---------------------------------------------------------------------------
#define PHASE8(p, a, b, STG, VM)                                               \
  {                                                                            \
    STG;                                                                       \
    if ((VM) == 10) asm volatile("s_waitcnt vmcnt(10)" ::: "memory");          \
    __builtin_amdgcn_s_barrier();                                              \
    const char* sA_ = smA + ((p) << 15) + ((a) << 14);                         \
    const char* sB_ = smB + ((p) << 15) + ((b) << 14);                         \
    bf16x8 av[4][2], bv[2][2];                                                 \
    _Pragma("unroll") for (int q = 0; q < 4; ++q) {                            \
      av[q][0] = *(const bf16x8*)(sA_ + aRow + q * 2048 + kh0);                \
      av[q][1] = *(const bf16x8*)(sA_ + aRow + q * 2048 + kh1);                \
    }                                                                          \
    _Pragma("unroll") for (int n_ = 0; n_ < 2; ++n_) {                         \
      bv[n_][0] = *(const bf16x8*)(sB_ + bRow + n_ * 2048 + kh0);              \
      bv[n_][1] = *(const bf16x8*)(sB_ + bRow + n_ * 2048 + kh1);              \
    }                                                                          \
    __builtin_amdgcn_s_setprio(1);                                             \
    _Pragma("unroll") for (int q = 0; q < 4; ++q)                              \
      _Pragma("unroll") for (int n_ = 0; n_ < 2; ++n_) {                       \
        acc[(a)*4 + q][(b)*2 + n_] = __builtin_amdgcn_mfma_f32_16x16x32_bf16(  \
            av[q][0], bv[n_][0], acc[(a)*4 + q][(b)*2 + n_], 0, 0, 0);         \
        acc[(a)*4 + q][(b)*2 + n_] = __builtin_amdgcn_mfma_f32_16x16x32_bf16(  \
            av[q][1], bv[n_][1], acc[(a)*4 + q][(b)*2 + n_], 0, 0, 0);         \
      }                                                                        \
    __builtin_amdgcn_s_setprio(0);                                             \
    __builtin_amdgcn_s_barrier();                                              \
  }

template <int EPI>  // 1 = QKV, 2 = fused SwiGLU, 3 = Wd split-K bf16 partial
__global__ __launch_bounds__(512, 2) void gemm256p(
    const bf16* __restrict__ A, const bf16* __restrict__ BT,
    const bf16* __restrict__ BT2, const float* __restrict__ bias,
    const float* __restrict__ bias2, bf16* __restrict__ outp,
    bf16* __restrict__ vout, bf16* __restrict__ pout,
    int Astr, int Bstr) {
  __shared__ char smem[131072];
  char* smA = smem;
  char* smB = smem + 65536;

  const int tid = threadIdx.x, wid = tid >> 6, lane = tid & 63;
  const int fr = lane & 15, fq = lane >> 4;
  const int wr = wid >> 2, wc = wid & 3;
  const int wm = wr * 128, wn = wc * 64;

  // T1 bijective XCD swizzle (all grids here are multiples of 8)
  int wg = blockIdx.x;
  {
    const int nwg = gridDim.x;
    int qq = nwg >> 3, rr = nwg & 7, xc = wg & 7, ix = wg >> 3;
    wg = (xc < rr ? xc * (qq + 1) : rr * (qq + 1) + (xc - rr) * qq) + ix;
  }
  int mtile, ntile, ks = 0;
  if constexpr (EPI == 3) { mtile = wg & 15; ntile = (wg >> 4) & 3; ks = wg >> 6; }
  else                    { mtile = wg & 15; ntile = wg >> 4; }
  const int m0 = mtile * 256;
  const int nbase = (EPI == 2) ? ntile * 128 : ntile * 256;
  const size_t kbase = (size_t)ks << 10;

  // ---- staging sources (T2 pre-swizzled segment) ----
  const int lr = tid >> 3;                       // 0..63
  const int segS = ((tid & 7) ^ (lr & 7)) * 8;   // elems
  const bf16* pAc0a0 = A + (size_t)(m0 + lr) * Astr + kbase + segS;
  const bf16* pAc0a1 = A + (size_t)(m0 + 64 + lr) * Astr + kbase + segS;
  const bf16* pAc1a0 = A + (size_t)(m0 + 128 + lr) * Astr + kbase + segS;
  const bf16* pAc1a1 = A + (size_t)(m0 + 192 + lr) * Astr + kbase + segS;
  const int nn0 = (lr >> 5) * 64 + (lr & 31);
  const bf16 *pBc0b0, *pBc0b1, *pBc1b0, *pBc1b1;
  if constexpr (EPI == 2) {
    pBc0b0 = BT  + (size_t)(nbase + nn0) * Bstr + kbase + segS;
    pBc0b1 = BT  + (size_t)(nbase + nn0 + 32) * Bstr + kbase + segS;
    pBc1b0 = BT2 + (size_t)(nbase + nn0) * Bstr + kbase + segS;
    pBc1b1 = BT2 + (size_t)(nbase + nn0 + 32) * Bstr + kbase + segS;
  } else {
    pBc0b0 = BT + (size_t)(nbase + nn0) * Bstr + kbase + segS;
    pBc0b1 = BT + (size_t)(nbase + nn0 + 32) * Bstr + kbase + segS;
    pBc1b0 = BT + (size_t)(nbase + 128 + nn0) * Bstr + kbase + segS;
    pBc1b1 = BT + (size_t)(nbase + 128 + nn0 + 32) * Bstr + kbase + segS;
  }
  const int widOff = wid * 1024;

  auto stA = [&](int p, int a, int kt) {
    const size_t ko = (size_t)kt * 64;
    char* d = smA + (p << 15) + (a << 14) + widOff;
    GLDS16((a ? pAc0a1 : pAc0a0) + ko, d);
    GLDS16((a ? pAc1a1 : pAc1a0) + ko, d + 8192);
  };
  auto stB = [&](int p, int b, int kt) {
    const size_t ko = (size_t)kt * 64;
    char* d = smB + (p << 15) + (b << 14) + widOff;
    GLDS16((b ? pBc0b1 : pBc0b0) + ko, d);
    GLDS16((b ? pBc1b1 : pBc1b0) + ko, d + 8192);
  };

  // ---- read addressing (T2 read-side XOR, per-lane constant) ----
  const int co0 = (fq * 16) ^ ((fr & 3) << 4);
  const int kh0 = (fr & 4) << 4;
  const int kh1 = 64 ^ kh0;
  const int aRow = (wr * 64 + fr) * 128 + co0;   // + q*2048 + kh
  const int bRow = (wc * 32 + fr) * 128 + co0;   // + n_*2048 + kh

  f32x4 acc[8][4];
#pragma unroll
  for (int i = 0; i < 8; ++i)
#pragma unroll
    for (int j = 0; j < 4; ++j) acc[i][j] = f32x4{0.f, 0.f, 0.f, 0.f};

  // ---- prologue: 6 sections (tiles 0 and 1 partial) ----
  stB(0, 0, 0); stA(0, 0, 0); stA(0, 1, 0); stB(0, 1, 0);
  stB(1, 0, 1); stA(1, 0, 1);

  for (int t2 = 0; t2 < 8; ++t2) {
    const int te = 2 * t2, to = te + 1;
    PHASE8(0, 0, 0, stA(1, 1, (te + 1) & 15), 10)
    PHASE8(0, 1, 0, stB(1, 1, (te + 1) & 15), 10)
    PHASE8(0, 0, 1, stB(0, 0, (te + 2) & 15), 10)
    PHASE8(0, 1, 1, stA(0, 0, (te + 2) & 15), -1)
    PHASE8(1, 0, 0, stA(0, 1, (to + 1) & 15), 10)
    PHASE8(1, 1, 0, stB(0, 1, (to + 1) & 15), 10)
    PHASE8(1, 0, 1, stB(1, 0, (to + 2) & 15), 10)
    PHASE8(1, 1, 1, stA(1, 0, (to + 2) & 15), -1)
  }
  asm volatile("s_waitcnt vmcnt(0)" ::: "memory");
  __builtin_amdgcn_s_barrier();

  if constexpr (EPI == 1) {
    if (nbase < 2048) {  // Q|K -> [4096][2048]
#pragma unroll
      for (int mi = 0; mi < 8; ++mi)
#pragma unroll
        for (int nj = 0; nj < 4; ++nj) {
          const int grow = m0 + wm + mi * 16 + fq * 4;
          const int gcol = nbase + wn + nj * 16 + fr;
          const float bc = bias[gcol];
#pragma unroll
          for (int r = 0; r < 4; ++r)
            outp[(size_t)(grow + r) * 2048 + gcol] = (bf16)(acc[mi][nj][r] + bc);
        }
    } else {  // V -> vT[(b*1024+d)][t]
#pragma unroll
      for (int mi = 0; mi < 8; ++mi)
#pragma unroll
        for (int nj = 0; nj < 4; ++nj) {
          const int grow = m0 + wm + mi * 16 + fq * 4;
          const int gcol = nbase + wn + nj * 16 + fr;
          const float bc = bias[gcol];
          bf16x4v pk;
#pragma unroll
          for (int r = 0; r < 4; ++r) pk[r] = (bf16)(acc[mi][nj][r] + bc);
          *(bf16x4v*)(vout + ((size_t)((grow >> 11) * 1024 + (gcol - 2048))) * 2048 +
                      (grow & 2047)) = pk;
        }
    }
  } else if constexpr (EPI == 2) {  // fused silu(g)*u
    float* uls = (float*)smem;      // [256][128] fp32 (safe: vmcnt(0)+barrier above)
    if (wn >= 128) {
#pragma unroll
      for (int mi = 0; mi < 8; ++mi)
#pragma unroll
        for (int nj = 0; nj < 4; ++nj) {
          const int rowL = wm + mi * 16 + fq * 4;
          const int cu = wn - 128 + nj * 16 + fr;
          const float bc = bias2[nbase + cu];
#pragma unroll
          for (int r = 0; r < 4; ++r)
            uls[(rowL + r) * 128 + cu] = acc[mi][nj][r] + bc;
        }
    }
    __syncthreads();
    if (wn < 128) {
#pragma unroll
      for (int mi = 0; mi < 8; ++mi)
#pragma unroll
        for (int nj = 0; nj < 4; ++nj) {
          const int rowL = wm + mi * 16 + fq * 4;
          const int cg = wn + nj * 16 + fr;
          const float bc = bias[nbase + cg];
#pragma unroll
          for (int r = 0; r < 4; ++r) {
            const float g = acc[mi][nj][r] + bc;
            const float u = uls[(rowL + r) * 128 + cg];
            outp[(size_t)(m0 + rowL + r) * 4096 + nbase + cg] =
                (bf16)(g * u / (1.f + __expf(-g)));
          }
        }
    }
  } else {  // EPI 3: bf16 partial [4096][1024] for split-K slice ks
    bf16* po = pout + ((size_t)ks << 22);   // 4M bf16 = 8MB per slice
#pragma unroll
    for (int mi = 0; mi < 8; ++mi)
#pragma unroll
      for (int nj = 0; nj < 4; ++nj) {
        const int grow = m0 + wm + mi * 16 + fq * 4;
        const int gcol = nbase + wn + nj * 16 + fr;
#pragma unroll
        for (int r = 0; r < 4; ++r)
          po[(size_t)(grow + r) * 1024 + gcol] = (bf16)acc[mi][nj][r];
      }
  }
}

// out = x1 + bd + sum_{k<4} parts[k]   (float4 per thread)
__global__ __launch_bounds__(256) void reduce_wd(
    const float* __restrict__ x1, const float* __restrict__ bd,
    const bf16* __restrict__ parts, float* __restrict__ out) {
  const size_t i = (size_t)blockIdx.x * 256 + threadIdx.x;
  const float4 a  = ((const float4*)x1)[i];
  const float4 bv = ((const float4*)bd)[i & 255];
  float s0 = a.x + bv.x, s1 = a.y + bv.y, s2 = a.z + bv.z, s3 = a.w + bv.w;
#pragma unroll
  for (int k = 0; k < 4; ++k) {
    const bf16x4v p = ((const bf16x4v*)(parts + ((size_t)k << 22)))[i];
    s0 += (float)p[0]; s1 += (float)p[1]; s2 += (float)p[2]; s3 += (float)p[3];
  }
  ((float4*)out)[i] = make_float4(s0, s1, s2, s3);
}

// ---------------------------------------------------------------------------
// m97-style 128x128 GEMM (Wo).  EPI 1: fp32 out + residual.
// ---------------------------------------------------------------------------
template <int EPI>
__global__ __launch_bounds__(256) void gemm_bf16t(
    const bf16* __restrict__ A, const bf16* __restrict__ BT,
    const float* __restrict__ bias, const float* __restrict__ res,
    void* __restrict__ Cout, int M, int N, int K) {
  __shared__ bf16 sA[128 * 64];
  __shared__ bf16 sB[128 * 64];
  const int tid = threadIdx.x;
  const int wid = tid >> 6, lane = tid & 63;
  const int m0 = blockIdx.y * 128, n0 = blockIdx.x * 128;
  const int wm = (wid >> 1) * 64, wn = (wid & 1) * 64;
  const int lrow = lane >> 3, lseg = (lane & 7) * 8;
  const int fr = lane & 15, fq = lane >> 4;

  f32x4 acc[4][4];
#pragma unroll
  for (int i = 0; i < 4; ++i)
#pragma unroll
    for (int j = 0; j < 4; ++j) acc[i][j] = f32x4{0.f, 0.f, 0.f, 0.f};

  for (int k0 = 0; k0 < K; k0 += 64) {
#pragma unroll
    for (int it = 0; it < 4; ++it) {
      const int c = wid * 4 + it;
      const int row = c * 8 + lrow;
      GLDS16(A  + (size_t)(m0 + row) * K + k0 + lseg, sA + c * 512);
      GLDS16(BT + (size_t)(n0 + row) * K + k0 + lseg, sB + c * 512);
    }
    __syncthreads();
#pragma unroll
    for (int kk = 0; kk < 64; kk += 32) {
      bf16x8 af[4], bfv[4];
#pragma unroll
      for (int i = 0; i < 4; ++i)
        af[i] = *(const bf16x8*)(sA + (wm + i * 16 + fr) * 64 + kk + 8 * fq);
#pragma unroll
      for (int j = 0; j < 4; ++j)
        bfv[j] = *(const bf16x8*)(sB + (wn + j * 16 + fr) * 64 + kk + 8 * fq);
#pragma unroll
      for (int i = 0; i < 4; ++i)
#pragma unroll
        for (int j = 0; j < 4; ++j)
          acc[i][j] = __builtin_amdgcn_mfma_f32_16x16x32_bf16(af[i], bfv[j],
                                                              acc[i][j], 0, 0, 0);
    }
    __syncthreads();
  }

#pragma unroll
  for (int i = 0; i < 4; ++i) {
    const int grow = m0 + wm + i * 16 + fq * 4;
#pragma unroll
    for (int j = 0; j < 4; ++j) {
      const int gcol = n0 + wn + j * 16 + fr;
      const float bc = bias[gcol];
#pragma unroll
      for (int r = 0; r < 4; ++r) {
        const size_t idx = (size_t)(grow + r) * N + gcol;
        const float v = acc[i][j][r] + bc;
        if constexpr (EPI == 1) {
          ((float*)Cout)[idx] = v + res[idx];
        } else {
          ((bf16*)Cout)[idx] = (bf16)v;
        }
      }
    }
  }
}

// ---------------------------------------------------------------------------
// MFMA windowed attention (qk stride 2048: Q at +0, K at +1024).
// ---------------------------------------------------------------------------
__global__ __launch_bounds__(256) void attn_mfma(const bf16* __restrict__ qk,
                                                 const bf16* __restrict__ vT,
                                                 bf16* __restrict__ ctx) {
  __shared__ bf16 sQ[64 * 72];
  __shared__ bf16 sK[320 * 72];
  __shared__ bf16 sVT[64 * 328];
  __shared__ bf16 sP[64 * 328];
  const int bh = blockIdx.x;
  const int b = bh >> 4, h = bh & 15;
  const int qs0 = blockIdx.y * 64;
  const int t0 = qs0 - 128;
  const int tS = t0 < 0 ? 0 : (t0 > S_LEN - 320 ? S_LEN - 320 : t0);
  const int tid = threadIdx.x, wid = tid >> 6, lane = tid & 63;
  const size_t bbase = (size_t)b * S_LEN;

#pragma unroll
  for (int i = 0; i < 10; ++i) {
    const int c = i * 256 + tid, row = c >> 3, seg = (c & 7) * 8;
    *(bf16x8*)(sK + row * 72 + seg) =
        *(const bf16x8*)(qk + (bbase + tS + row) * 2048 + 1024 + h * 64 + seg);
  }
#pragma unroll
  for (int i = 0; i < 2; ++i) {
    const int c = i * 256 + tid, row = c >> 3, seg = (c & 7) * 8;
    *(bf16x8*)(sQ + row * 72 + seg) =
        *(const bf16x8*)(qk + (bbase + qs0 + row) * 2048 + h * 64 + seg);
  }
  {
    const int row = tid >> 2;
    const size_t vbase = ((size_t)bh * 64 + row) * 2048 + tS;
#pragma unroll
    for (int i = 0; i < 10; ++i) {
      const int seg = ((tid & 3) + 4 * i) * 8;
      *(bf16x8*)(sVT + row * 328 + seg) = *(const bf16x8*)(vT + vbase + seg);
    }
  }
  __syncthreads();

  const int fr = lane & 15, fq = lane >> 4;

  f32x4 s[20];
#pragma unroll
  for (int j = 0; j < 20; ++j) s[j] = f32x4{0.f, 0.f, 0.f, 0.f};
#pragma unroll
  for (int kk = 0; kk < 64; kk += 32) {
    const bf16x8 aq = *(const bf16x8*)(sQ + (wid * 16 + fr) * 72 + kk + 8 * fq);
#pragma unroll
    for (int j = 0; j < 20; ++j) {
      const bf16x8 bk = *(const bf16x8*)(sK + (j * 16 + fr) * 72 + kk + 8 * fq);
      s[j] = __builtin_amdgcn_mfma_f32_16x16x32_bf16(aq, bk, s[j], 0, 0, 0);
    }
  }

#pragma unroll
  for (int r = 0; r < 4; ++r) {
    const int q_g = qs0 + wid * 16 + fq * 4 + r;
    float m = -1e30f;
#pragma unroll
    for (int j = 0; j < 20; ++j) {
      const int t_g = tS + j * 16 + fr;
      const bool ok = (unsigned)(q_g - t_g + 128) <= 256u;
      const float val = ok ? s[j][r] * 0.125f : -1e30f;
      s[j][r] = val;
      m = fmaxf(m, val);
    }
#pragma unroll
    for (int off = 1; off < 16; off <<= 1) m = fmaxf(m, __shfl_xor(m, off));
    float sm = 0.f;
#pragma unroll
    for (int j = 0; j < 20; ++j) {
      const float p = __expf(s[j][r] - m);
      s[j][r] = p;
      sm += p;
    }
#pragma unroll
    for (int off = 1; off < 16; off <<= 1) sm += __shfl_xor(sm, off);
    const float inv = 1.f / sm;
#pragma unroll
    for (int j = 0; j < 20; ++j)
      sP[(wid * 16 + fq * 4 + r) * 328 + j * 16 + fr] = (bf16)(s[j][r] * inv);
  }
  __syncthreads();

  f32x4 o[4];
#pragma unroll
  for (int j = 0; j < 4; ++j) o[j] = f32x4{0.f, 0.f, 0.f, 0.f};
#pragma unroll
  for (int ks = 0; ks < 10; ++ks) {
    const int kk = ks * 32;
    const bf16x8 pa = *(const bf16x8*)(sP + (wid * 16 + fr) * 328 + kk + 8 * fq);
#pragma unroll
    for (int j = 0; j < 4; ++j) {
      const bf16x8 vb = *(const bf16x8*)(sVT + (j * 16 + fr) * 328 + kk + 8 * fq);
      o[j] = __builtin_amdgcn_mfma_f32_16x16x32_bf16(pa, vb, o[j], 0, 0, 0);
    }
  }
#pragma unroll
  for (int j = 0; j < 4; ++j)
#pragma unroll
    for (int r = 0; r < 4; ++r) {
      const int q = qs0 + wid * 16 + fq * 4 + r;
      ctx[(bbase + q) * 1024 + h * 64 + j * 16 + fr] = (bf16)o[j][r];
    }
}

// ---------------------------------------------------------------------------
extern "C" void kernel_launch(void* const* d_in, const int* in_sizes, int n_in,
                              void* d_out, int out_size, void* d_ws, size_t ws_size,
                              hipStream_t stream) {
  const float* x    = (const float*)d_in[0];
  const float* ln1w = (const float*)d_in[2];
  const float* ln1b = (const float*)d_in[3];
  const float* Wq   = (const float*)d_in[4];
  const float* bq   = (const float*)d_in[5];
  const float* Wk   = (const float*)d_in[6];
  const float* bk   = (const float*)d_in[7];
  const float* Wv   = (const float*)d_in[8];
  const float* bv   = (const float*)d_in[9];
  const float* Wo   = (const float*)d_in[10];
  const float* bo   = (const float*)d_in[11];
  const float* ln2w = (const float*)d_in[12];
  const float* ln2b = (const float*)d_in[13];
  const float* Wg   = (const float*)d_in[14];
  const float* bg   = (const float*)d_in[15];
  const float* Wu   = (const float*)d_in[16];
  const float* bu   = (const float*)d_in[17];
  const float* Wd   = (const float*)d_in[18];
  const float* bd   = (const float*)d_in[19];

  char* ws = (char*)d_ws;
  size_t off = 0;
  auto take = [&](size_t bytes) {
    char* p = ws + off;
    off += (bytes + 255) & ~(size_t)255;
    return p;
  };
  bf16*  wqkvT = (bf16*)take((size_t)3072 * 1024 * 2);
  bf16*  woT   = (bf16*)take((size_t)1024 * 1024 * 2);
  bf16*  wgT   = (bf16*)take((size_t)4096 * 1024 * 2);
  bf16*  wuT   = (bf16*)take((size_t)4096 * 1024 * 2);
  bf16*  wdT   = (bf16*)take((size_t)1024 * 4096 * 2);
  float* bqkv  = (float*)take((size_t)3072 * 4);
  bf16*  h     = (bf16*)take((size_t)4096 * 1024 * 2);   // 8MB  } h..vT: 40MB
  bf16*  qk    = (bf16*)take((size_t)4096 * 2048 * 2);   // 16MB } contiguous,
  bf16*  ctx   = (bf16*)take((size_t)4096 * 1024 * 2);   // 8MB  } dead by Wd;
  bf16*  vT    = (bf16*)take((size_t)2048 * 2048 * 2);   // 8MB  } partials=32MB
  float* x1    = (float*)take((size_t)4096 * 1024 * 4);
  bf16*  h2    = (bf16*)take((size_t)4096 * 1024 * 2);
  bf16*  gated = (bf16*)take((size_t)4096 * 4096 * 2);
  bf16*  parts = h;   // 4 x 4M bf16 slices over h,qk,ctx,vT (32MB <= 40MB)
  (void)ws_size; (void)in_sizes; (void)n_in; (void)out_size;

  const dim3 tb(32, 8);
  tr_cast<<<dim3(32, 32), tb, 0, stream>>>(Wq, wqkvT, 1024, 1024);
  tr_cast<<<dim3(32, 32), tb, 0, stream>>>(Wk, wqkvT + (size_t)1024 * 1024, 1024, 1024);
  tr_cast<<<dim3(32, 32), tb, 0, stream>>>(Wv, wqkvT + (size_t)2048 * 1024, 1024, 1024);
  tr_cast<<<dim3(32, 32), tb, 0, stream>>>(Wo, woT, 1024, 1024);
  tr_cast<<<dim3(128, 32), tb, 0, stream>>>(Wg, wgT, 1024, 4096);
  tr_cast<<<dim3(128, 32), tb, 0, stream>>>(Wu, wuT, 1024, 4096);
  tr_cast<<<dim3(32, 128), tb, 0, stream>>>(Wd, wdT, 4096, 1024);
  concat3<<<12, 256, 0, stream>>>(bq, bk, bv, bqkv);

  // LN1 -> h
  ln_bf16<<<4096, 256, 0, stream>>>(x, ln1w, ln1b, h);
  // QKV: Q|K -> qk (stride 2048), V -> vT transposed.  grid 16m x 12n.
  gemm256p<1><<<192, 512, 0, stream>>>(h, wqkvT, nullptr, bqkv, nullptr,
                                       qk, vT, nullptr, 1024, 1024);
  // windowed attention -> ctx bf16
  attn_mfma<<<dim3(32, 32), 256, 0, stream>>>(qk, vT, ctx);
  // x1 = x + ctx @ Wo + bo
  gemm_bf16t<1><<<dim3(8, 32), 256, 0, stream>>>(ctx, woT, bo, x,
                                                 x1, 4096, 1024, 1024);
  // LN2 -> h2
  ln_bf16<<<4096, 256, 0, stream>>>(x1, ln2w, ln2b, h2);
  // gated = silu(h2@Wg+bg) * (h2@Wu+bu)   (fused, grid 16m x 32 n-halves)
  gemm256p<2><<<512, 512, 0, stream>>>(h2, wgT, wuT, bg, bu, gated,
                                       nullptr, nullptr, 1024, 1024);
  // Wd split-K=4 (grid 16m x 4n x 4k): bf16 partials, then final reduce
  gemm256p<3><<<256, 512, 0, stream>>>(gated, wdT, nullptr, nullptr, nullptr,
                                       nullptr, nullptr, parts, 4096, 4096);
  reduce_wd<<<4096, 256, 0, stream>>>(x1, bd, parts, (float*)d_out);
}

// Round 7
// 262.870 us; speedup vs baseline: 2.3480x; 1.0110x over previous
//
#include <hip/hip_runtime.h>
#include <stdint.h>

// ---------------------------------------------------------------------------
// WindowedSelfAttentionLayer: B=2 S=2048 D=1024 H=16 HID=4096 WIN=256
//  - gemm256p: 256x256-tile, 8-wave, BK=64, K=1024/slice.  Min-read pipeline:
//    per K-tile stage ALL of tile t+1 into other parity (8 gloads), counted
//    vmcnt(8), 24 ds_read_b128/tile/wave (bv held across a-halves), 64 MFMA,
//    2 barriers.  T1 XCD swizzle, T2 XOR seg swizzle, T5 setprio.
//    EPI1=QKV (Q|K + V-transposed), EPI2=fused SwiGLU, EPI3=Wd splitK bf16.
//  - gemm_bf16t: m97-style 128x128 kernel for Wo.
//  - attn_mfma: MFMA flash-style windowed attention.
// ---------------------------------------------------------------------------

typedef __bf16 bf16;
typedef bf16  bf16x8 __attribute__((ext_vector_type(8)));
typedef bf16  bf16x4v __attribute__((ext_vector_type(4)));
typedef float f32x4  __attribute__((ext_vector_type(4)));

#define S_LEN 2048

#define GLDS16(gp, lp)                                                          \
  __builtin_amdgcn_global_load_lds(                                            \
      (__attribute__((address_space(1))) void*)(gp),                            \
      (__attribute__((address_space(3))) void*)(lp), 16, 0, 0)

// ---------------------------------------------------------------------------
__global__ __launch_bounds__(256) void ln_bf16(const float* __restrict__ x,
                                               const float* __restrict__ w,
                                               const float* __restrict__ bb,
                                               bf16* __restrict__ out) {
  const int row = blockIdx.x, tid = threadIdx.x;
  const int wid = tid >> 6, lane = tid & 63;
  const float4 v = ((const float4*)(x + (size_t)row * 1024))[tid];
  float s = v.x + v.y + v.z + v.w;
  float q = v.x * v.x + v.y * v.y + v.z * v.z + v.w * v.w;
#pragma unroll
  for (int off = 32; off > 0; off >>= 1) {
    s += __shfl_xor(s, off);
    q += __shfl_xor(q, off);
  }
  __shared__ float rs_[4], rq_[4];
  if (lane == 0) { rs_[wid] = s; rq_[wid] = q; }
  __syncthreads();
  s = rs_[0] + rs_[1] + rs_[2] + rs_[3];
  q = rq_[0] + rq_[1] + rq_[2] + rq_[3];
  const float mean = s * (1.f / 1024.f);
  const float var  = q * (1.f / 1024.f) - mean * mean;
  const float rstd = rsqrtf(var + 1e-5f);
  const float4 wv = ((const float4*)w)[tid];
  const float4 bv = ((const float4*)bb)[tid];
  bf16x4v o;
  o[0] = (bf16)((v.x - mean) * rstd * wv.x + bv.x);
  o[1] = (bf16)((v.y - mean) * rstd * wv.y + bv.y);
  o[2] = (bf16)((v.z - mean) * rstd * wv.z + bv.z);
  o[3] = (bf16)((v.w - mean) * rstd * wv.w + bv.w);
  ((bf16x4v*)(out + (size_t)row * 1024))[tid] = o;
}

// ---------------------------------------------------------------------------
__global__ __launch_bounds__(256) void tr_cast(const float* __restrict__ in,
                                               bf16* __restrict__ out, int R, int C) {
  __shared__ float t[32][33];
  const int tx = threadIdx.x, ty = threadIdx.y;
  const int r0 = blockIdx.y * 32, c0 = blockIdx.x * 32;
#pragma unroll
  for (int i = 0; i < 4; ++i)
    t[ty + 8 * i][tx] = in[(size_t)(r0 + ty + 8 * i) * C + c0 + tx];
  __syncthreads();
#pragma unroll
  for (int i = 0; i < 4; ++i)
    out[(size_t)(c0 + ty + 8 * i) * R + r0 + tx] = (bf16)t[tx][ty + 8 * i];
}

__global__ void concat3(const float* __restrict__ a, const float* __restrict__ b,
                        const float* __restrict__ c, float* __restrict__ o) {
  int i = blockIdx.x * 256 + threadIdx.x;
  if (i < 1024) o[i] = a[i];
  else if (i < 2048) o[i] = b[i - 1024];
  else if (i < 3072) o[i] = c[i - 2048];
}

// ---------------------------------------------------------------------------
// Min-read 256x256 GEMM, K=1024/slice (16 K-tiles), 512 thr = 8 waves
// (2M x 4N), per wave 128x64 out = 8x4 frags.  LDS 128KB: A/B each
// [parity][256 rows][128 B] linear, T2 swizzle: row r phys seg s holds
// global seg s^(r&7) (pre-swizzled global src; read addr XORs fr&7).
// Per K-tile t (parity P=t&1):
//   STAGE all 8 chunks of tile t+1 -> parity P^1      [lead = 1 full tile]
//   vmcnt(8)  (8 outstanding from t+1; waits t's 8)   + barrier
//   kh0: read bv[4],av[4](a=0) -> 16 MFMA; read av[4](a=1) -> 16 MFMA
//   kh1: same                                          (24 b128 total)
//   barrier   (all waves done reading P before t+1 body stages into P)
// ---------------------------------------------------------------------------
template <int EPI>  // 1 = QKV, 2 = fused SwiGLU, 3 = Wd split-K bf16 partial
__global__ __launch_bounds__(512, 2) void gemm256p(
    const bf16* __restrict__ A, const bf16* __restrict__ BT,
    const bf16* __restrict__ BT2, const float* __restrict__ bias,
    const float* __restrict__ bias2, bf16* __restrict__ outp,
    bf16* __restrict__ vout, bf16* __restrict__ pout,
    int Astr, int Bstr) {
  __shared__ char smem[131072];
  char* A0 = smem;
  char* A1 = smem + 32768;
  char* B0 = smem + 65536;
  char* B1 = smem + 98304;

  const int tid = threadIdx.x, wid = tid >> 6, lane = tid & 63;
  const int fr = lane & 15, fq = lane >> 4;
  const int wr = wid >> 2, wc = wid & 3;
  const int wm = wr * 128, wn = wc * 64;

  // T1 bijective XCD swizzle (all grids here are multiples of 8)
  int wg = blockIdx.x;
  {
    const int nwg = gridDim.x;
    int qq = nwg >> 3, rr = nwg & 7, xc = wg & 7, ix = wg >> 3;
    wg = (xc < rr ? xc * (qq + 1) : rr * (qq + 1) + (xc - rr) * qq) + ix;
  }
  int mtile, ntile, ks = 0;
  if constexpr (EPI == 3) { mtile = wg & 15; ntile = (wg >> 4) & 3; ks = wg >> 6; }
  else                    { mtile = wg & 15; ntile = wg >> 4; }
  const int m0 = mtile * 256;
  const int nbase = (EPI == 2) ? ntile * 128 : ntile * 256;
  const size_t kbase = (size_t)ks << 10;

  // ---- staging sources (T2 pre-swizzled segment), chunk rows 8-aligned ----
  const int srow = lane >> 3;                          // 0..7 within chunk
  const int segS = ((lane & 7) ^ srow) * 8;            // elems
  const size_t rsA8 = (size_t)8 * Astr;                // 8-row chunk stride
  const size_t rsB8 = (size_t)8 * Bstr;
  const bf16* pA = A + (size_t)(m0 + wid * 32 + srow) * Astr + kbase + segS;
  const bf16* pB;
  if constexpr (EPI == 2) {
    const bf16* srcB = (wid < 4) ? BT : BT2;           // rows 0-127 g, 128-255 u
    pB = srcB + (size_t)(nbase + (wid & 3) * 32 + srow) * Bstr + kbase + segS;
  } else {
    pB = BT + (size_t)(nbase + wid * 32 + srow) * Bstr + kbase + segS;
  }
  const int cOff = wid * 4096;  // 4 chunks x 1KB per wave

  auto STAGE = [&](char* aD, char* bD, int kt) {
    const size_t ko = (size_t)kt * 64;
#pragma unroll
    for (int i = 0; i < 4; ++i) {
      GLDS16(pA + i * rsA8 + ko, aD + cOff + i * 1024);
      GLDS16(pB + i * rsB8 + ko, bD + cOff + i * 1024);
    }
  };

  // ---- read addressing (T2 read-side XOR, per-lane constant) ----
  const int co0 = (fq * 16) ^ ((fr & 3) << 4);
  const int kh0 = (fr & 4) << 4;          // phys offset of logical k-half 0
  const int kh1 = 64 ^ kh0;
  const int aOff = (wm + fr) * 128 + co0;  // + mi*2048 + khX
  const int bOff = (wn + fr) * 128 + co0;  // + nj*2048 + khX

  f32x4 acc[8][4];
#pragma unroll
  for (int i = 0; i < 8; ++i)
#pragma unroll
    for (int j = 0; j < 4; ++j) acc[i][j] = f32x4{0.f, 0.f, 0.f, 0.f};

  auto COMPUTE = [&](const char* aB, const char* bB) {
#pragma unroll
    for (int kh = 0; kh < 2; ++kh) {
      const int khX = kh ? kh1 : kh0;
      bf16x8 bv[4], av[4];
#pragma unroll
      for (int nj = 0; nj < 4; ++nj)
        bv[nj] = *(const bf16x8*)(bB + bOff + nj * 2048 + khX);
#pragma unroll
      for (int q = 0; q < 4; ++q)
        av[q] = *(const bf16x8*)(aB + aOff + q * 2048 + khX);
      __builtin_amdgcn_s_setprio(1);
#pragma unroll
      for (int q = 0; q < 4; ++q)
#pragma unroll
        for (int nj = 0; nj < 4; ++nj)
          acc[q][nj] = __builtin_amdgcn_mfma_f32_16x16x32_bf16(
              av[q], bv[nj], acc[q][nj], 0, 0, 0);
      __builtin_amdgcn_s_setprio(0);
#pragma unroll
      for (int q = 0; q < 4; ++q)
        av[q] = *(const bf16x8*)(aB + aOff + 8192 + q * 2048 + khX);
      __builtin_amdgcn_s_setprio(1);
#pragma unroll
      for (int q = 0; q < 4; ++q)
#pragma unroll
        for (int nj = 0; nj < 4; ++nj)
          acc[4 + q][nj] = __builtin_amdgcn_mfma_f32_16x16x32_bf16(
              av[q], bv[nj], acc[4 + q][nj], 0, 0, 0);
      __builtin_amdgcn_s_setprio(0);
    }
  };

#define VM8()  asm volatile("s_waitcnt vmcnt(8)" ::: "memory")
#define VM0()  asm volatile("s_waitcnt vmcnt(0)" ::: "memory")
#define BAR()  __builtin_amdgcn_s_barrier()

  // prologue: tile 0 into parity 0
  STAGE(A0, B0, 0);
  // tiles 0..14 with prefetch; tile kt parity = kt&1
#pragma unroll 1
  for (int t2 = 0; t2 < 7; ++t2) {
    STAGE(A1, B1, 2 * t2 + 1);  VM8();  BAR();
    COMPUTE(A0, B0);            BAR();
    STAGE(A0, B0, 2 * t2 + 2);  VM8();  BAR();
    COMPUTE(A1, B1);            BAR();
  }
  STAGE(A1, B1, 15);  VM8();  BAR();
  COMPUTE(A0, B0);    BAR();
  VM0();  BAR();
  COMPUTE(A1, B1);    BAR();

  if constexpr (EPI == 1) {
    if (nbase < 2048) {  // Q|K -> [4096][2048]
#pragma unroll
      for (int mi = 0; mi < 8; ++mi)
#pragma unroll
        for (int nj = 0; nj < 4; ++nj) {
          const int grow = m0 + wm + mi * 16 + fq * 4;
          const int gcol = nbase + wn + nj * 16 + fr;
          const float bc = bias[gcol];
#pragma unroll
          for (int r = 0; r < 4; ++r)
            outp[(size_t)(grow + r) * 2048 + gcol] = (bf16)(acc[mi][nj][r] + bc);
        }
    } else {  // V -> vT[(b*1024+d)][t]
#pragma unroll
      for (int mi = 0; mi < 8; ++mi)
#pragma unroll
        for (int nj = 0; nj < 4; ++nj) {
          const int grow = m0 + wm + mi * 16 + fq * 4;
          const int gcol = nbase + wn + nj * 16 + fr;
          const float bc = bias[gcol];
          bf16x4v pk;
#pragma unroll
          for (int r = 0; r < 4; ++r) pk[r] = (bf16)(acc[mi][nj][r] + bc);
          *(bf16x4v*)(vout + ((size_t)((grow >> 11) * 1024 + (gcol - 2048))) * 2048 +
                      (grow & 2047)) = pk;
        }
    }
  } else if constexpr (EPI == 2) {  // fused silu(g)*u
    float* uls = (float*)smem;      // [256][128] fp32 (reads drained above)
    if (wn >= 128) {
#pragma unroll
      for (int mi = 0; mi < 8; ++mi)
#pragma unroll
        for (int nj = 0; nj < 4; ++nj) {
          const int rowL = wm + mi * 16 + fq * 4;
          const int cu = wn - 128 + nj * 16 + fr;
          const float bc = bias2[nbase + cu];
#pragma unroll
          for (int r = 0; r < 4; ++r)
            uls[(rowL + r) * 128 + cu] = acc[mi][nj][r] + bc;
        }
    }
    __syncthreads();
    if (wn < 128) {
#pragma unroll
      for (int mi = 0; mi < 8; ++mi)
#pragma unroll
        for (int nj = 0; nj < 4; ++nj) {
          const int rowL = wm + mi * 16 + fq * 4;
          const int cg = wn + nj * 16 + fr;
          const float bc = bias[nbase + cg];
#pragma unroll
          for (int r = 0; r < 4; ++r) {
            const float g = acc[mi][nj][r] + bc;
            const float u = uls[(rowL + r) * 128 + cg];
            outp[(size_t)(m0 + rowL + r) * 4096 + nbase + cg] =
                (bf16)(g * u / (1.f + __expf(-g)));
          }
        }
    }
  } else {  // EPI 3: bf16 partial [4096][1024] for split-K slice ks
    bf16* po = pout + ((size_t)ks << 22);
#pragma unroll
    for (int mi = 0; mi < 8; ++mi)
#pragma unroll
      for (int nj = 0; nj < 4; ++nj) {
        const int grow = m0 + wm + mi * 16 + fq * 4;
        const int gcol = nbase + wn + nj * 16 + fr;
#pragma unroll
        for (int r = 0; r < 4; ++r)
          po[(size_t)(grow + r) * 1024 + gcol] = (bf16)acc[mi][nj][r];
      }
  }
#undef VM8
#undef VM0
#undef BAR
}

// out = x1 + bd + sum_{k<4} parts[k]   (float4 per thread)
__global__ __launch_bounds__(256) void reduce_wd(
    const float* __restrict__ x1, const float* __restrict__ bd,
    const bf16* __restrict__ parts, float* __restrict__ out) {
  const size_t i = (size_t)blockIdx.x * 256 + threadIdx.x;
  const float4 a  = ((const float4*)x1)[i];
  const float4 bv = ((const float4*)bd)[i & 255];
  float s0 = a.x + bv.x, s1 = a.y + bv.y, s2 = a.z + bv.z, s3 = a.w + bv.w;
#pragma unroll
  for (int k = 0; k < 4; ++k) {
    const bf16x4v p = ((const bf16x4v*)(parts + ((size_t)k << 22)))[i];
    s0 += (float)p[0]; s1 += (float)p[1]; s2 += (float)p[2]; s3 += (float)p[3];
  }
  ((float4*)out)[i] = make_float4(s0, s1, s2, s3);
}

// ---------------------------------------------------------------------------
// m97-style 128x128 GEMM (Wo).  EPI 1: fp32 out + residual.
// ---------------------------------------------------------------------------
template <int EPI>
__global__ __launch_bounds__(256) void gemm_bf16t(
    const bf16* __restrict__ A, const bf16* __restrict__ BT,
    const float* __restrict__ bias, const float* __restrict__ res,
    void* __restrict__ Cout, int M, int N, int K) {
  __shared__ bf16 sA[128 * 64];
  __shared__ bf16 sB[128 * 64];
  const int tid = threadIdx.x;
  const int wid = tid >> 6, lane = tid & 63;
  const int m0 = blockIdx.y * 128, n0 = blockIdx.x * 128;
  const int wm = (wid >> 1) * 64, wn = (wid & 1) * 64;
  const int lrow = lane >> 3, lseg = (lane & 7) * 8;
  const int fr = lane & 15, fq = lane >> 4;

  f32x4 acc[4][4];
#pragma unroll
  for (int i = 0; i < 4; ++i)
#pragma unroll
    for (int j = 0; j < 4; ++j) acc[i][j] = f32x4{0.f, 0.f, 0.f, 0.f};

  for (int k0 = 0; k0 < K; k0 += 64) {
#pragma unroll
    for (int it = 0; it < 4; ++it) {
      const int c = wid * 4 + it;
      const int row = c * 8 + lrow;
      GLDS16(A  + (size_t)(m0 + row) * K + k0 + lseg, sA + c * 512);
      GLDS16(BT + (size_t)(n0 + row) * K + k0 + lseg, sB + c * 512);
    }
    __syncthreads();
#pragma unroll
    for (int kk = 0; kk < 64; kk += 32) {
      bf16x8 af[4], bfv[4];
#pragma unroll
      for (int i = 0; i < 4; ++i)
        af[i] = *(const bf16x8*)(sA + (wm + i * 16 + fr) * 64 + kk + 8 * fq);
#pragma unroll
      for (int j = 0; j < 4; ++j)
        bfv[j] = *(const bf16x8*)(sB + (wn + j * 16 + fr) * 64 + kk + 8 * fq);
#pragma unroll
      for (int i = 0; i < 4; ++i)
#pragma unroll
        for (int j = 0; j < 4; ++j)
          acc[i][j] = __builtin_amdgcn_mfma_f32_16x16x32_bf16(af[i], bfv[j],
                                                              acc[i][j], 0, 0, 0);
    }
    __syncthreads();
  }

#pragma unroll
  for (int i = 0; i < 4; ++i) {
    const int grow = m0 + wm + i * 16 + fq * 4;
#pragma unroll
    for (int j = 0; j < 4; ++j) {
      const int gcol = n0 + wn + j * 16 + fr;
      const float bc = bias[gcol];
#pragma unroll
      for (int r = 0; r < 4; ++r) {
        const size_t idx = (size_t)(grow + r) * N + gcol;
        const float v = acc[i][j][r] + bc;
        if constexpr (EPI == 1) {
          ((float*)Cout)[idx] = v + res[idx];
        } else {
          ((bf16*)Cout)[idx] = (bf16)v;
        }
      }
    }
  }
}

// ---------------------------------------------------------------------------
// MFMA windowed attention (qk stride 2048: Q at +0, K at +1024).
// ---------------------------------------------------------------------------
__global__ __launch_bounds__(256) void attn_mfma(const bf16* __restrict__ qk,
                                                 const bf16* __restrict__ vT,
                                                 bf16* __restrict__ ctx) {
  __shared__ bf16 sQ[64 * 72];
  __shared__ bf16 sK[320 * 72];
  __shared__ bf16 sVT[64 * 328];
  __shared__ bf16 sP[64 * 328];
  const int bh = blockIdx.x;
  const int b = bh >> 4, h = bh & 15;
  const int qs0 = blockIdx.y * 64;
  const int t0 = qs0 - 128;
  const int tS = t0 < 0 ? 0 : (t0 > S_LEN - 320 ? S_LEN - 320 : t0);
  const int tid = threadIdx.x, wid = tid >> 6, lane = tid & 63;
  const size_t bbase = (size_t)b * S_LEN;

#pragma unroll
  for (int i = 0; i < 10; ++i) {
    const int c = i * 256 + tid, row = c >> 3, seg = (c & 7) * 8;
    *(bf16x8*)(sK + row * 72 + seg) =
        *(const bf16x8*)(qk + (bbase + tS + row) * 2048 + 1024 + h * 64 + seg);
  }
#pragma unroll
  for (int i = 0; i < 2; ++i) {
    const int c = i * 256 + tid, row = c >> 3, seg = (c & 7) * 8;
    *(bf16x8*)(sQ + row * 72 + seg) =
        *(const bf16x8*)(qk + (bbase + qs0 + row) * 2048 + h * 64 + seg);
  }
  {
    const int row = tid >> 2;
    const size_t vbase = ((size_t)bh * 64 + row) * 2048 + tS;
#pragma unroll
    for (int i = 0; i < 10; ++i) {
      const int seg = ((tid & 3) + 4 * i) * 8;
      *(bf16x8*)(sVT + row * 328 + seg) = *(const bf16x8*)(vT + vbase + seg);
    }
  }
  __syncthreads();

  const int fr = lane & 15, fq = lane >> 4;

  f32x4 s[20];
#pragma unroll
  for (int j = 0; j < 20; ++j) s[j] = f32x4{0.f, 0.f, 0.f, 0.f};
#pragma unroll
  for (int kk = 0; kk < 64; kk += 32) {
    const bf16x8 aq = *(const bf16x8*)(sQ + (wid * 16 + fr) * 72 + kk + 8 * fq);
#pragma unroll
    for (int j = 0; j < 20; ++j) {
      const bf16x8 bk = *(const bf16x8*)(sK + (j * 16 + fr) * 72 + kk + 8 * fq);
      s[j] = __builtin_amdgcn_mfma_f32_16x16x32_bf16(aq, bk, s[j], 0, 0, 0);
    }
  }

#pragma unroll
  for (int r = 0; r < 4; ++r) {
    const int q_g = qs0 + wid * 16 + fq * 4 + r;
    float m = -1e30f;
#pragma unroll
    for (int j = 0; j < 20; ++j) {
      const int t_g = tS + j * 16 + fr;
      const bool ok = (unsigned)(q_g - t_g + 128) <= 256u;
      const float val = ok ? s[j][r] * 0.125f : -1e30f;
      s[j][r] = val;
      m = fmaxf(m, val);
    }
#pragma unroll
    for (int off = 1; off < 16; off <<= 1) m = fmaxf(m, __shfl_xor(m, off));
    float sm = 0.f;
#pragma unroll
    for (int j = 0; j < 20; ++j) {
      const float p = __expf(s[j][r] - m);
      s[j][r] = p;
      sm += p;
    }
#pragma unroll
    for (int off = 1; off < 16; off <<= 1) sm += __shfl_xor(sm, off);
    const float inv = 1.f / sm;
#pragma unroll
    for (int j = 0; j < 20; ++j)
      sP[(wid * 16 + fq * 4 + r) * 328 + j * 16 + fr] = (bf16)(s[j][r] * inv);
  }
  __syncthreads();

  f32x4 o[4];
#pragma unroll
  for (int j = 0; j < 4; ++j) o[j] = f32x4{0.f, 0.f, 0.f, 0.f};
#pragma unroll
  for (int ks = 0; ks < 10; ++ks) {
    const int kk = ks * 32;
    const bf16x8 pa = *(const bf16x8*)(sP + (wid * 16 + fr) * 328 + kk + 8 * fq);
#pragma unroll
    for (int j = 0; j < 4; ++j) {
      const bf16x8 vb = *(const bf16x8*)(sVT + (j * 16 + fr) * 328 + kk + 8 * fq);
      o[j] = __builtin_amdgcn_mfma_f32_16x16x32_bf16(pa, vb, o[j], 0, 0, 0);
    }
  }
#pragma unroll
  for (int j = 0; j < 4; ++j)
#pragma unroll
    for (int r = 0; r < 4; ++r) {
      const int q = qs0 + wid * 16 + fq * 4 + r;
      ctx[(bbase + q) * 1024 + h * 64 + j * 16 + fr] = (bf16)o[j][r];
    }
}

// ---------------------------------------------------------------------------
extern "C" void kernel_launch(void* const* d_in, const int* in_sizes, int n_in,
                              void* d_out, int out_size, void* d_ws, size_t ws_size,
                              hipStream_t stream) {
  const float* x    = (const float*)d_in[0];
  const float* ln1w = (const float*)d_in[2];
  const float* ln1b = (const float*)d_in[3];
  const float* Wq   = (const float*)d_in[4];
  const float* bq   = (const float*)d_in[5];
  const float* Wk   = (const float*)d_in[6];
  const float* bk   = (const float*)d_in[7];
  const float* Wv   = (const float*)d_in[8];
  const float* bv   = (const float*)d_in[9];
  const float* Wo   = (const float*)d_in[10];
  const float* bo   = (const float*)d_in[11];
  const float* ln2w = (const float*)d_in[12];
  const float* ln2b = (const float*)d_in[13];
  const float* Wg   = (const float*)d_in[14];
  const float* bg   = (const float*)d_in[15];
  const float* Wu   = (const float*)d_in[16];
  const float* bu   = (const float*)d_in[17];
  const float* Wd   = (const float*)d_in[18];
  const float* bd   = (const float*)d_in[19];

  char* ws = (char*)d_ws;
  size_t off = 0;
  auto take = [&](size_t bytes) {
    char* p = ws + off;
    off += (bytes + 255) & ~(size_t)255;
    return p;
  };
  bf16*  wqkvT = (bf16*)take((size_t)3072 * 1024 * 2);
  bf16*  woT   = (bf16*)take((size_t)1024 * 1024 * 2);
  bf16*  wgT   = (bf16*)take((size_t)4096 * 1024 * 2);
  bf16*  wuT   = (bf16*)take((size_t)4096 * 1024 * 2);
  bf16*  wdT   = (bf16*)take((size_t)1024 * 4096 * 2);
  float* bqkv  = (float*)take((size_t)3072 * 4);
  bf16*  h     = (bf16*)take((size_t)4096 * 1024 * 2);   // 8MB  } h..vT: 40MB
  bf16*  qk    = (bf16*)take((size_t)4096 * 2048 * 2);   // 16MB } contiguous,
  bf16*  ctx   = (bf16*)take((size_t)4096 * 1024 * 2);   // 8MB  } dead by Wd;
  bf16*  vT    = (bf16*)take((size_t)2048 * 2048 * 2);   // 8MB  } partials=32MB
  float* x1    = (float*)take((size_t)4096 * 1024 * 4);
  bf16*  h2    = (bf16*)take((size_t)4096 * 1024 * 2);
  bf16*  gated = (bf16*)take((size_t)4096 * 4096 * 2);
  bf16*  parts = h;   // 4 x 4M bf16 slices over h,qk,ctx,vT (32MB <= 40MB)
  (void)ws_size; (void)in_sizes; (void)n_in; (void)out_size;

  const dim3 tb(32, 8);
  tr_cast<<<dim3(32, 32), tb, 0, stream>>>(Wq, wqkvT, 1024, 1024);
  tr_cast<<<dim3(32, 32), tb, 0, stream>>>(Wk, wqkvT + (size_t)1024 * 1024, 1024, 1024);
  tr_cast<<<dim3(32, 32), tb, 0, stream>>>(Wv, wqkvT + (size_t)2048 * 1024, 1024, 1024);
  tr_cast<<<dim3(32, 32), tb, 0, stream>>>(Wo, woT, 1024, 1024);
  tr_cast<<<dim3(128, 32), tb, 0, stream>>>(Wg, wgT, 1024, 4096);
  tr_cast<<<dim3(128, 32), tb, 0, stream>>>(Wu, wuT, 1024, 4096);
  tr_cast<<<dim3(32, 128), tb, 0, stream>>>(Wd, wdT, 4096, 1024);
  concat3<<<12, 256, 0, stream>>>(bq, bk, bv, bqkv);

  // LN1 -> h
  ln_bf16<<<4096, 256, 0, stream>>>(x, ln1w, ln1b, h);
  // QKV: Q|K -> qk (stride 2048), V -> vT transposed.  grid 16m x 12n.
  gemm256p<1><<<192, 512, 0, stream>>>(h, wqkvT, nullptr, bqkv, nullptr,
                                       qk, vT, nullptr, 1024, 1024);
  // windowed attention -> ctx bf16
  attn_mfma<<<dim3(32, 32), 256, 0, stream>>>(qk, vT, ctx);
  // x1 = x + ctx @ Wo + bo
  gemm_bf16t<1><<<dim3(8, 32), 256, 0, stream>>>(ctx, woT, bo, x,
                                                 x1, 4096, 1024, 1024);
  // LN2 -> h2
  ln_bf16<<<4096, 256, 0, stream>>>(x1, ln2w, ln2b, h2);
  // gated = silu(h2@Wg+bg) * (h2@Wu+bu)   (fused, grid 16m x 32 n-halves)
  gemm256p<2><<<512, 512, 0, stream>>>(h2, wgT, wuT, bg, bu, gated,
                                       nullptr, nullptr, 1024, 1024);
  // Wd split-K=4 (grid 16m x 4n x 4k): bf16 partials, then final reduce
  gemm256p<3><<<256, 512, 0, stream>>>(gated, wdT, nullptr, nullptr, nullptr,
                                       nullptr, nullptr, parts, 4096, 4096);
  reduce_wd<<<4096, 256, 0, stream>>>(x1, bd, parts, (float*)d_out);
}